// Round 7
// baseline (954.148 us; speedup 1.0000x reference)
//
#include <hip/hip_runtime.h>
#include <hip/hip_bf16.h>
#include <float.h>
#include <math.h>

typedef __hip_bfloat16 bf16;

#define B_ 16
#define N_ 1000
#define E_ 4000
#define L_ 64
#define A_ 128
#define D_ 256
#define H_ 4
#define HD_ 1024
#define SCALE_ 0.0625f

typedef __attribute__((ext_vector_type(8))) short short8;
typedef __attribute__((ext_vector_type(4))) float f32x4;

union U4S8 { uint4 u; short8 s; };

__device__ __forceinline__ unsigned short f2bf(float f) {
    bf16 h = __float2bfloat16(f);
    return *reinterpret_cast<unsigned short*>(&h);
}
__device__ __forceinline__ unsigned pack2(float a, float b) {
    return (unsigned)f2bf(a) | ((unsigned)f2bf(b) << 16);
}
__device__ __forceinline__ float bflo(unsigned u) { return __uint_as_float(u << 16); }
__device__ __forceinline__ float bfhi(unsigned u) { return __uint_as_float(u & 0xffff0000u); }

// ---------------------------------------------------------------------------
// Pre-pass kernels
// ---------------------------------------------------------------------------
__global__ void convemb_kernel(const float* __restrict__ src, bf16* __restrict__ dst, long n4)
{
    long i = (long)blockIdx.x * 256 + threadIdx.x;
    if (i >= n4) return;
    float4 v = *(const float4*)(src + i * 4);
    *(uint2*)(dst + i * 4) = make_uint2(pack2(v.x, v.y), pack2(v.z, v.w));
}

__global__ void pack_w_kernel(const float* __restrict__ src, unsigned* __restrict__ dst,
                              int K, int N, int dstN, int colOff, int trans)
{
    int idx = blockIdx.x * 256 + threadIdx.x;
    if (idx >= (K / 2) * N) return;
    int k2 = idx / N, n = idx % N;
    float a, b;
    if (!trans) { a = src[(long)(2 * k2) * N + n]; b = src[(long)(2 * k2 + 1) * N + n]; }
    else        { a = src[(long)n * K + 2 * k2];   b = src[(long)n * K + 2 * k2 + 1]; }
    dst[(long)k2 * dstN + colOff + n] = pack2(a, b);
}

// W_hh [768,256] -> MFMA B-fragment stream: index ((tile*8+tk)*64+lane) -> short8
// frag element j = W_hh[n = tile*16 + (lane&15)][k = tk*32 + (lane>>4)*8 + j]
__global__ void pack_whh_kernel(const float* __restrict__ W_hh, short8* __restrict__ dst)
{
    int idx = blockIdx.x * 256 + threadIdx.x;   // 48*8*64 = 24576
    if (idx >= 24576) return;
    int lane = idx & 63;
    int tk = (idx >> 6) & 7;
    int tile = idx >> 9;
    int n = tile * 16 + (lane & 15);
    const float* wp = W_hh + (long)n * 256 + tk * 32 + (lane >> 4) * 8;
    float4 w0 = *(const float4*)wp;
    float4 w1 = *(const float4*)(wp + 4);
    U4S8 u;
    u.u = make_uint4(pack2(w0.x, w0.y), pack2(w0.z, w0.w),
                     pack2(w1.x, w1.y), pack2(w1.z, w1.w));
    dst[idx] = u.s;
}

__global__ void bias4_kernel(const float* b0, const float* b1, const float* b2,
                             const float* b3, float* __restrict__ dst)
{
    int i = blockIdx.x * 256 + threadIdx.x;
    if (i >= 4096) return;
    int q = i >> 10, c = i & 1023;
    const float* s = (q == 0) ? b0 : (q == 1) ? b1 : (q == 2) ? b2 : b3;
    dst[i] = s[c];
}

// ---------------------------------------------------------------------------
// MFMA GEMM: C[M,Nc] = act( gatherA[M,K](bf16) @ Bp(packed bf16) + bias )
// ---------------------------------------------------------------------------
#define TM 128
#define TN 128
#define TK 32
#define ASTR 40
#define BSTR 132

template <typename CT>
__global__ __launch_bounds__(256)
void pgemm_kernel(const bf16* __restrict__ A, const int* __restrict__ arows,
                  const unsigned* __restrict__ Bp, const float* __restrict__ bias,
                  CT* __restrict__ C, int M, int K, int Nc, int relu_out)
{
    __shared__ short    As[TM * ASTR];
    __shared__ unsigned Bs[(TK / 2) * BSTR];

    const int tid  = threadIdx.x;
    const int lane = tid & 63;
    const int wave = tid >> 6;
    const int wm = wave >> 1, wn = wave & 1;
    const int quad = lane >> 4, c16 = lane & 15;
    const long row0 = (long)blockIdx.y * TM;
    const int  col0 = blockIdx.x * TN;

    const int sm  = tid >> 1;
    const int sh  = (tid & 1) * 16;
    const int sn2 = tid & 63;
    const int skk = (tid >> 6) * 4;

    long gr_row = row0 + sm;
    if (gr_row > M - 1) gr_row = M - 1;
    long ar = arows ? (long)arows[gr_row] : gr_row;
    const short* Arow = (const short*)A + ar * K + sh;

    f32x4 acc[4][4];
    #pragma unroll
    for (int i = 0; i < 4; ++i)
        #pragma unroll
        for (int j = 0; j < 4; ++j)
            acc[i][j] = (f32x4){0.f, 0.f, 0.f, 0.f};

    for (int k0 = 0; k0 < K; k0 += TK) {
        {
            const short* p = Arow + k0;
            uint4 a = *(const uint4*)(p);
            uint4 b = *(const uint4*)(p + 8);
            *(uint4*)&As[sm * ASTR + sh]     = a;
            *(uint4*)&As[sm * ASTR + sh + 8] = b;
        }
        #pragma unroll
        for (int i = 0; i < 4; ++i) {
            int kk2 = skk + i;
            *(uint2*)&Bs[kk2 * BSTR + sn2 * 2] =
                *(const uint2*)&Bp[(long)(k0 / 2 + kk2) * Nc + col0 + sn2 * 2];
        }
        __syncthreads();

        short8 af[4];
        U4S8   bfr[4];
        #pragma unroll
        for (int mi = 0; mi < 4; ++mi) {
            int m = wm * 64 + mi * 16 + c16;
            af[mi] = *(const short8*)&As[m * ASTR + quad * 8];
        }
        #pragma unroll
        for (int ni = 0; ni < 4; ++ni) {
            int n = wn * 64 + ni * 16 + c16;
            uint4 u;
            u.x = Bs[(quad * 4 + 0) * BSTR + n];
            u.y = Bs[(quad * 4 + 1) * BSTR + n];
            u.z = Bs[(quad * 4 + 2) * BSTR + n];
            u.w = Bs[(quad * 4 + 3) * BSTR + n];
            bfr[ni].u = u;
        }
        #pragma unroll
        for (int mi = 0; mi < 4; ++mi)
            #pragma unroll
            for (int ni = 0; ni < 4; ++ni)
                acc[mi][ni] = __builtin_amdgcn_mfma_f32_16x16x32_bf16(
                    af[mi], bfr[ni].s, acc[mi][ni], 0, 0, 0);
        __syncthreads();
    }

    #pragma unroll
    for (int ni = 0; ni < 4; ++ni) {
        int col = col0 + wn * 64 + ni * 16 + c16;
        float bv = bias ? bias[col] : 0.f;
        #pragma unroll
        for (int mi = 0; mi < 4; ++mi) {
            long row = row0 + wm * 64 + mi * 16 + quad * 4;
            #pragma unroll
            for (int r = 0; r < 4; ++r) {
                if (row + r >= M) continue;
                float v = acc[mi][ni][r] + bv;
                if (relu_out) v = fmaxf(v, 0.f);
                C[(row + r) * Nc + col] = (CT)v;
            }
        }
    }
}

// ---------------------------------------------------------------------------
// CSR build
// ---------------------------------------------------------------------------
__global__ void zero_int_kernel(int* __restrict__ p, int n)
{
    int i = blockIdx.x * 256 + threadIdx.x;
    if (i < n) p[i] = 0;
}

__global__ void count_kernel(const int* __restrict__ edge_index, int b0,
                             int* __restrict__ cnt, int cE)
{
    int i = blockIdx.x * 256 + threadIdx.x;
    if (i >= cE) return;
    int bl = i / E_, ei = i % E_;
    int dst = edge_index[(long)(b0 + bl) * 2 * E_ + E_ + ei];
    atomicAdd(&cnt[bl * N_ + dst], 1);
}

__global__ __launch_bounds__(1024)
void scan_kernel(const int* __restrict__ cnt, int* __restrict__ row_start,
                 int* __restrict__ cursor)
{
    int bl = blockIdx.x;
    int tid = threadIdx.x;
    __shared__ int s[1024];
    int v = (tid < N_) ? cnt[bl * N_ + tid] : 0;
    s[tid] = v;
    __syncthreads();
    for (int off = 1; off < 1024; off <<= 1) {
        int t = (tid >= off) ? s[tid - off] : 0;
        __syncthreads();
        s[tid] += t;
        __syncthreads();
    }
    if (tid < N_) {
        int excl = s[tid] - v;
        row_start[bl * N_ + tid] = excl;
        cursor[bl * N_ + tid] = excl;
    }
}

__global__ void scatter_kernel(const int* __restrict__ edge_index, int b0,
                               int* __restrict__ cursor, int* __restrict__ elist, int cE)
{
    int i = blockIdx.x * 256 + threadIdx.x;
    if (i >= cE) return;
    int bl = i / E_, ei = i % E_;
    int dst = edge_index[(long)(b0 + bl) * 2 * E_ + E_ + ei];
    int pos = atomicAdd(&cursor[bl * N_ + dst], 1);
    elist[bl * E_ + pos] = ei;
}

// ---------------------------------------------------------------------------
// alpha_ex on fused qkvs buffer (stride 4096: q@0, k@1024, v@2048, skip@3072)
// ---------------------------------------------------------------------------
__device__ __forceinline__ float qke2(unsigned q, unsigned k, unsigned e)
{
    return bflo(q) * (bflo(k) + bflo(e)) + bfhi(q) * (bfhi(k) + bfhi(e));
}

__global__ void alpha_ex_kernel(const bf16* __restrict__ qkvs, const bf16* __restrict__ e,
                                const int* __restrict__ edge_index,
                                int b0, float* __restrict__ ex, int cE)
{
    int eidx = blockIdx.x * 4 + (threadIdx.x >> 6);
    int l = threadIdx.x & 63;
    int bl = eidx / E_, ei = eidx % E_;
    const int* eb = edge_index + (long)(b0 + bl) * 2 * E_;
    int src = eb[ei], dst = eb[E_ + ei];
    int head = l >> 4;
    int j0 = head * 256 + (l & 15) * 16;

    const uint4* qp = (const uint4*)(qkvs + (long)(bl * N_ + dst) * 4096 + j0);
    const uint4* kp = (const uint4*)(qkvs + (long)(bl * N_ + src) * 4096 + 1024 + j0);
    const uint4* ep = (const uint4*)(e + (long)eidx * HD_ + j0);

    uint4 qa = qp[0], qb2 = qp[1];
    uint4 ka = kp[0], kb2 = kp[1];
    uint4 ea = ep[0], eb2 = ep[1];

    float s = qke2(qa.x, ka.x, ea.x) + qke2(qa.y, ka.y, ea.y)
            + qke2(qa.z, ka.z, ea.z) + qke2(qa.w, ka.w, ea.w)
            + qke2(qb2.x, kb2.x, eb2.x) + qke2(qb2.y, kb2.y, eb2.y)
            + qke2(qb2.z, kb2.z, eb2.z) + qke2(qb2.w, kb2.w, eb2.w);

    s += __shfl_down(s, 8);
    s += __shfl_down(s, 4);
    s += __shfl_down(s, 2);
    s += __shfl_down(s, 1);

    if ((l & 15) == 0)
        ex[(long)head * cE + eidx] = expf(s * SCALE_);
}

// ---------------------------------------------------------------------------
// agg_node: CSR reduce + normalize + skip + ReLU -> bf16
// ---------------------------------------------------------------------------
__global__ void agg_node_kernel(const bf16* __restrict__ qkvs, const bf16* __restrict__ e,
                                const float* __restrict__ ex, const int* __restrict__ edge_index,
                                const int* __restrict__ row_start, const int* __restrict__ cnt,
                                const int* __restrict__ elist,
                                int b0, int cE, bf16* __restrict__ aggb)
{
    int base = blockIdx.x;
    int bl = base / N_;
    int tid = threadIdx.x;
    int h = tid >> 6;
    int j0 = tid * 4;

    int start = row_start[base];
    int deg = cnt[base];
    const int* el = elist + (long)bl * E_;
    const float* exh = ex + (long)h * cE;
    const int* srcp = edge_index + (long)(b0 + bl) * 2 * E_;

    float d = 0.f;
    for (int t = 0; t < deg; ++t)
        d += exh[(long)bl * E_ + el[start + t]];
    float invd = (deg > 0) ? 1.f / d : 0.f;

    float a0 = 0.f, a1 = 0.f, a2 = 0.f, a3 = 0.f;
    for (int t = 0; t < deg; ++t) {
        int ei = el[start + t];
        long eidx = (long)bl * E_ + ei;
        float w = exh[eidx] * invd;
        int src = srcp[ei];
        uint2 vv = *(const uint2*)(qkvs + (long)(bl * N_ + src) * 4096 + 2048 + j0);
        uint2 ee = *(const uint2*)(e + eidx * HD_ + j0);
        a0 += w * (bflo(vv.x) + bflo(ee.x));
        a1 += w * (bfhi(vv.x) + bfhi(ee.x));
        a2 += w * (bflo(vv.y) + bflo(ee.y));
        a3 += w * (bfhi(vv.y) + bfhi(ee.y));
    }

    uint2 sk = *(const uint2*)(qkvs + (long)base * 4096 + 3072 + j0);
    unsigned o0 = pack2(fmaxf(bflo(sk.x) + a0, 0.f), fmaxf(bfhi(sk.x) + a1, 0.f));
    unsigned o1 = pack2(fmaxf(bflo(sk.y) + a2, 0.f), fmaxf(bfhi(sk.y) + a3, 0.f));
    *(uint2*)(aggb + (long)base * HD_ + j0) = make_uint2(o0, o1);
}

// ---------------------------------------------------------------------------
// mixed embed -> bf16
// ---------------------------------------------------------------------------
__global__ void mixed_kernel(const bf16* __restrict__ embh, const int* __restrict__ tok,
                             const int* __restrict__ node, const float* __restrict__ graph_repr,
                             int rows_per_batch, bf16* __restrict__ out)
{
    int r = blockIdx.x;
    int b = r / rows_per_batch;
    int d = threadIdx.x;
    float v = (float)embh[(long)tok[r] * D_ + d] +
              graph_repr[((long)b * N_ + node[r]) * D_ + d];
    out[(long)r * D_ + d] = __float2bfloat16(v);
}

// ---------------------------------------------------------------------------
// GRU via MFMA: one block, 16 waves (1024 thr).  3 n-tiles/wave -> wfrag =
// 96 VGPRs (+acc 12 + temps) fits the 128-VGPR cap at 4 waves/SIMD BY
// CONSTRUCTION (no spill).  Weights pre-packed to fragment order (coalesced).
// No dynamically-indexed per-thread arrays.  gx bf16 loaded each step before
// the MFMA phase (latency hidden).  Elementwise: 1024 thr x 4 h-elements.
// ---------------------------------------------------------------------------
#define GSTR 780

__global__ __launch_bounds__(1024)
void gru_kernel(const bf16* __restrict__ gxh, const short8* __restrict__ WhhP,
                const float* __restrict__ b_hh, float* __restrict__ inv_out)
{
    __shared__ float gatesLDS[16 * GSTR];   // 49920 B
    __shared__ short hB[16 * 264];          // 8448 B

    const int tid = threadIdx.x;
    const int lane = tid & 63;
    const int wave = tid >> 6;              // 0..15
    const int quad = lane >> 4, col = lane & 15;

    for (int i = tid; i < 16 * 264; i += 1024) hB[i] = 0;

    // weight fragments: tiles 3w..3w+2, all register-resident
    short8 wfrag[3][8];
    float bhh[3];
    #pragma unroll
    for (int i = 0; i < 3; ++i) {
        int tile = wave * 3 + i;
        bhh[i] = b_hh[tile * 16 + col];
        #pragma unroll
        for (int tk = 0; tk < 8; ++tk)
            wfrag[i][tk] = WhhP[(tile * 8 + tk) * 64 + lane];
    }

    const int em = tid >> 6;        // batch 0..15 (== wave)
    const int c0 = (tid & 63) * 4;  // 4-wide col group
    float myh0 = 0.f, myh1 = 0.f, myh2 = 0.f, myh3 = 0.f;

    __syncthreads();

    for (int t = 0; t < L_; ++t) {
        // load gx (bf16) for this step; consumed after the barrier
        const short* gp = (const short*)gxh + ((long)em * L_ + t) * 768 + c0;
        uint2 xr2 = *(const uint2*)(gp);
        uint2 xz2 = *(const uint2*)(gp + 256);
        uint2 xn2 = *(const uint2*)(gp + 512);

        // MFMA: gates = h @ W_hh^T + b_hh
        f32x4 acc0 = (f32x4){bhh[0], bhh[0], bhh[0], bhh[0]};
        f32x4 acc1 = (f32x4){bhh[1], bhh[1], bhh[1], bhh[1]};
        f32x4 acc2 = (f32x4){bhh[2], bhh[2], bhh[2], bhh[2]};
        #pragma unroll
        for (int tk = 0; tk < 8; ++tk) {
            short8 a = *(const short8*)&hB[col * 264 + tk * 32 + quad * 8];
            acc0 = __builtin_amdgcn_mfma_f32_16x16x32_bf16(a, wfrag[0][tk], acc0, 0, 0, 0);
            acc1 = __builtin_amdgcn_mfma_f32_16x16x32_bf16(a, wfrag[1][tk], acc1, 0, 0, 0);
            acc2 = __builtin_amdgcn_mfma_f32_16x16x32_bf16(a, wfrag[2][tk], acc2, 0, 0, 0);
        }
        // write gates to [m][n] layout
        #pragma unroll
        for (int r = 0; r < 4; ++r) {
            int m = quad * 4 + r;
            gatesLDS[m * GSTR + (wave * 3 + 0) * 16 + col] = acc0[r];
            gatesLDS[m * GSTR + (wave * 3 + 1) * 16 + col] = acc1[r];
            gatesLDS[m * GSTR + (wave * 3 + 2) * 16 + col] = acc2[r];
        }
        __syncthreads();

        // elementwise: thread owns h[em][c0 .. c0+3]
        const float* g = &gatesLDS[em * GSTR + c0];
        float4 grv = *(const float4*)(g);
        float4 gzv = *(const float4*)(g + 256);
        float4 gnv = *(const float4*)(g + 512);
        float gr[4] = {grv.x, grv.y, grv.z, grv.w};
        float gz[4] = {gzv.x, gzv.y, gzv.z, gzv.w};
        float gn[4] = {gnv.x, gnv.y, gnv.z, gnv.w};
        float xr[4] = {bflo(xr2.x), bfhi(xr2.x), bflo(xr2.y), bfhi(xr2.y)};
        float xz[4] = {bflo(xz2.x), bfhi(xz2.x), bflo(xz2.y), bfhi(xz2.y)};
        float xn[4] = {bflo(xn2.x), bfhi(xn2.x), bflo(xn2.y), bfhi(xn2.y)};
        float hn[4];
        float hold[4] = {myh0, myh1, myh2, myh3};
        #pragma unroll
        for (int j = 0; j < 4; ++j) {
            float r = 1.f / (1.f + __expf(-(xr[j] + gr[j])));
            float z = 1.f / (1.f + __expf(-(xz[j] + gz[j])));
            float pre = xn[j] + r * gn[j];
            pre = fminf(fmaxf(pre, -15.f), 15.f);
            float e2 = __expf(-2.f * pre);
            float cc = (1.f - e2) / (1.f + e2);
            hn[j] = (1.f - z) * cc + z * hold[j];
        }
        myh0 = hn[0]; myh1 = hn[1]; myh2 = hn[2]; myh3 = hn[3];
        *(uint2*)&hB[em * 264 + c0] =
            make_uint2(pack2(hn[0], hn[1]), pack2(hn[2], hn[3]));
        __syncthreads();
    }

    float* op = inv_out + (long)em * 256 + c0;
    *(float4*)op = make_float4(myh0, myh1, myh2, myh3);
}

// ---------------------------------------------------------------------------
// scores (aa_emb bf16, aa_p f32)
// ---------------------------------------------------------------------------
__global__ void score_kernel(const float* __restrict__ aa_p, const bf16* __restrict__ aa_emb,
                             const float* __restrict__ inv, const float* __restrict__ Wab,
                             const float* __restrict__ bab, const float* __restrict__ mask,
                             float* __restrict__ out)
{
    int r = blockIdx.x * 4 + (threadIdx.x >> 6);
    int l = threadIdx.x & 63;
    int b = r / A_;
    float s = 0.f;
    for (int d = l; d < D_; d += 64)
        s += aa_p[(long)r * D_ + d] * inv[(long)b * D_ + d] +
             (float)aa_emb[(long)r * D_ + d] * Wab[d];
    #pragma unroll
    for (int off = 32; off; off >>= 1) s += __shfl_down(s, off);
    if (l == 0) {
        float lm = logf(mask[r]);
        const float MN = -3.4028234663852886e38f;
        if (!(lm >= MN)) lm = MN;
        out[r] = s + bab[0] + lm;
    }
}

// ---------------------------------------------------------------------------
// host
// ---------------------------------------------------------------------------
static inline size_t align256(size_t x) { return (x + 255) & ~(size_t)255; }

template <typename CT>
static void launch_pgemm(const bf16* A, const int* arows, const unsigned* Bp,
                         const float* bias, CT* C, int M, int K, int Nc, int relu,
                         hipStream_t s)
{
    dim3 grid(Nc / TN, (M + TM - 1) / TM);
    pgemm_kernel<CT><<<grid, 256, 0, s>>>(A, arows, Bp, bias, C, M, K, Nc, relu);
}

static void launch_pack(const float* src, unsigned* dst, int K, int N, int dstN,
                        int colOff, int trans, hipStream_t s)
{
    int tot = (K / 2) * N;
    pack_w_kernel<<<(tot + 255) / 256, 256, 0, s>>>(src, dst, K, N, dstN, colOff, trans);
}

extern "C" void kernel_launch(void* const* d_in, const int* in_sizes, int n_in,
                              void* d_out, int out_size, void* d_ws, size_t ws_size,
                              hipStream_t stream)
{
    const int* node_tokens = (const int*)d_in[0];
    const int* edge_tokens = (const int*)d_in[1];
    const int* edge_index  = (const int*)d_in[2];
    const int* inv_token   = (const int*)d_in[3];
    const int* inv_node    = (const int*)d_in[4];
    const int* aa_token    = (const int*)d_in[5];
    const int* aa_node     = (const int*)d_in[6];
    const float* action_mask = (const float*)d_in[7];
    const float* emb   = (const float*)d_in[8];
    const float* Wq    = (const float*)d_in[9];
    const float* bq    = (const float*)d_in[10];
    const float* Wk    = (const float*)d_in[11];
    const float* bk    = (const float*)d_in[12];
    const float* Wv    = (const float*)d_in[13];
    const float* bv    = (const float*)d_in[14];
    const float* We    = (const float*)d_in[15];
    const float* Wskip = (const float*)d_in[16];
    const float* bskip = (const float*)d_in[17];
    const float* W1    = (const float*)d_in[18];
    const float* b1    = (const float*)d_in[19];
    const float* Wp    = (const float*)d_in[20];
    const float* bp    = (const float*)d_in[21];
    const float* W_ih  = (const float*)d_in[22];
    const float* W_hh  = (const float*)d_in[23];
    const float* b_ih  = (const float*)d_in[24];
    const float* b_hh  = (const float*)d_in[25];
    const float* Wab   = (const float*)d_in[26];
    const float* bab   = (const float*)d_in[27];
    const float* Wap   = (const float*)d_in[28];
    const float* bap   = (const float*)d_in[29];
    (void)in_sizes; (void)n_in; (void)out_size;

    char* base = (char*)d_ws;
    size_t off = 0;
    auto alloc = [&](size_t bytes) -> char* {
        char* p = base + off;
        off = align256(off + bytes);
        return p;
    };

    // persistent buffers
    const long VD = 50000L * 256;
    bf16*  embh       = (bf16*)alloc(VD * 2);
    float* graph_repr = (float*)alloc((size_t)B_ * N_ * D_ * 4);
    bf16*  mixed_inv  = (bf16*)alloc((size_t)B_ * L_ * D_ * 2);
    bf16*  inv_h      = (bf16*)alloc((size_t)B_ * L_ * D_ * 2);
    bf16*  gxh        = (bf16*)alloc((size_t)B_ * L_ * 768 * 2);
    float* inv_out    = (float*)alloc((size_t)B_ * 256 * 4);
    bf16*  aa_emb     = (bf16*)alloc((size_t)B_ * A_ * D_ * 2);
    float* aa_p       = (float*)alloc((size_t)B_ * A_ * 256 * 4);
    unsigned* qkvsP   = (unsigned*)alloc((size_t)128 * 4096 * 4);
    unsigned* WeP     = (unsigned*)alloc((size_t)128 * 1024 * 4);
    unsigned* W1P     = (unsigned*)alloc((size_t)512 * 256 * 4);
    unsigned* WpP     = (unsigned*)alloc((size_t)128 * 256 * 4);
    unsigned* WihP    = (unsigned*)alloc((size_t)128 * 768 * 4);
    unsigned* WapP    = (unsigned*)alloc((size_t)128 * 256 * 4);
    short8* WhhP      = (short8*)alloc((size_t)24576 * 16);
    float* bias4096   = (float*)alloc(4096 * 4);
    size_t persist = off;

    // batch-chunk size
    int c = 16;
    while (c > 1) {
        size_t cN = (size_t)c * N_, cEs = (size_t)c * E_;
        size_t chunk = align256(cN * 4096 * 2)
                     + align256(cEs * HD_ * 2)
                     + align256(cN * HD_ * 2)
                     + align256(cEs * H_ * 4)
                     + 3 * align256(cN * 4)
                     + align256(cEs * 4);
        if (persist + chunk <= ws_size) break;
        c >>= 1;
    }
    int cN = c * N_, cE = c * E_;

    bf16*  qkvs  = (bf16*)alloc((size_t)cN * 4096 * 2);
    bf16*  ebuf  = (bf16*)alloc((size_t)cE * HD_ * 2);
    bf16*  aggb  = (bf16*)alloc((size_t)cN * HD_ * 2);
    float* ex    = (float*)alloc((size_t)cE * H_ * 4);
    int*   cnt   = (int*)alloc((size_t)cN * 4);
    int*   rstart= (int*)alloc((size_t)cN * 4);
    int*   cursor= (int*)alloc((size_t)cN * 4);
    int*   elist = (int*)alloc((size_t)cE * 4);

    // ---- pre-pass: conversions & weight packing ----
    convemb_kernel<<<(int)((VD / 4 + 255) / 256), 256, 0, stream>>>(emb, embh, VD / 4);
    launch_pack(Wq,    qkvsP, 256, 1024, 4096, 0,    0, stream);
    launch_pack(Wk,    qkvsP, 256, 1024, 4096, 1024, 0, stream);
    launch_pack(Wv,    qkvsP, 256, 1024, 4096, 2048, 0, stream);
    launch_pack(Wskip, qkvsP, 256, 1024, 4096, 3072, 0, stream);
    launch_pack(We,    WeP,   256, 1024, 1024, 0,    0, stream);
    launch_pack(W1,    W1P,  1024,  256,  256, 0,    0, stream);
    launch_pack(Wp,    WpP,   256,  256,  256, 0,    0, stream);
    launch_pack(W_ih,  WihP,  256,  768,  768, 0,    1, stream);
    launch_pack(Wap,   WapP,  256,  256,  256, 0,    0, stream);
    pack_whh_kernel<<<(24576 + 255) / 256, 256, 0, stream>>>(W_hh, WhhP);
    bias4_kernel<<<16, 256, 0, stream>>>(bq, bk, bv, bskip, bias4096);

    for (int b0 = 0; b0 < B_; b0 += c) {
        // CSR
        zero_int_kernel<<<(cN + 255) / 256, 256, 0, stream>>>(cnt, cN);
        count_kernel<<<(cE + 255) / 256, 256, 0, stream>>>(edge_index, b0, cnt, cE);
        scan_kernel<<<c, 1024, 0, stream>>>(cnt, rstart, cursor);
        scatter_kernel<<<(cE + 255) / 256, 256, 0, stream>>>(edge_index, b0, cursor,
                                                             elist, cE);
        // fused q|k|v|skip projection + edge projection
        launch_pgemm<bf16>(embh, node_tokens + (long)b0 * N_, qkvsP, bias4096, qkvs,
                           cN, D_, 4096, 0, stream);
        launch_pgemm<bf16>(embh, edge_tokens + (long)b0 * E_, WeP, nullptr, ebuf,
                           cE, D_, HD_, 0, stream);
        // attention
        alpha_ex_kernel<<<cE / 4, 256, 0, stream>>>(qkvs, ebuf, edge_index, b0, ex, cE);
        agg_node_kernel<<<cN, 256, 0, stream>>>(qkvs, ebuf, ex, edge_index, rstart, cnt,
                                                elist, b0, cE, aggb);
        // graph_repr = relu(aggb @ W1 + b1)
        launch_pgemm<float>(aggb, nullptr, W1P, b1,
                            graph_repr + (long)b0 * N_ * D_, cN, HD_, D_, 1, stream);
    }

    // invariant path
    mixed_kernel<<<B_ * L_, 256, 0, stream>>>(embh, inv_token, inv_node, graph_repr,
                                              L_, mixed_inv);
    launch_pgemm<bf16>(mixed_inv, nullptr, WpP, bp, inv_h, B_ * L_, D_, 256, 1, stream);
    launch_pgemm<bf16>(inv_h, nullptr, WihP, b_ih, gxh, B_ * L_, 256, 768, 0, stream);
    gru_kernel<<<1, 1024, 0, stream>>>(gxh, WhhP, b_hh, inv_out);

    // action path
    mixed_kernel<<<B_ * A_, 256, 0, stream>>>(embh, aa_token, aa_node, graph_repr,
                                              A_, aa_emb);
    launch_pgemm<float>(aa_emb, nullptr, WapP, bap, aa_p, B_ * A_, D_, 256, 0, stream);
    score_kernel<<<(B_ * A_) / 4, 256, 0, stream>>>(aa_p, aa_emb, inv_out, Wab, bab,
                                                    action_mask, (float*)d_out);
}

// Round 8
// 906.922 us; speedup vs baseline: 1.0521x; 1.0521x over previous
//
#include <hip/hip_runtime.h>
#include <hip/hip_bf16.h>
#include <float.h>
#include <math.h>

typedef __hip_bfloat16 bf16;

#define B_ 16
#define N_ 1000
#define E_ 4000
#define L_ 64
#define A_ 128
#define D_ 256
#define H_ 4
#define HD_ 1024
#define SCALE_ 0.0625f

typedef __attribute__((ext_vector_type(8))) short short8;
typedef __attribute__((ext_vector_type(4))) float f32x4;

union U4S8 { uint4 u; short8 s; };

__device__ __forceinline__ unsigned short f2bf(float f) {
    bf16 h = __float2bfloat16(f);
    return *reinterpret_cast<unsigned short*>(&h);
}
__device__ __forceinline__ unsigned pack2(float a, float b) {
    return (unsigned)f2bf(a) | ((unsigned)f2bf(b) << 16);
}
// fast RNE bf16 pair pack (no NaN handling needed here)
__device__ __forceinline__ unsigned rne2(float a, float b) {
    unsigned ua = __float_as_uint(a), ub = __float_as_uint(b);
    ua += 0x7fff + ((ua >> 16) & 1);
    ub += 0x7fff + ((ub >> 16) & 1);
    return (ua >> 16) | (ub & 0xffff0000u);
}
__device__ __forceinline__ float bflo(unsigned u) { return __uint_as_float(u << 16); }
__device__ __forceinline__ float bfhi(unsigned u) { return __uint_as_float(u & 0xffff0000u); }

#define LOG2E 1.4426950408889634f
__device__ __forceinline__ float fsigm(float x) {
    return __builtin_amdgcn_rcpf(1.f + __builtin_amdgcn_exp2f(-LOG2E * x));
}
__device__ __forceinline__ float ftanh(float x) {
    return 1.f - 2.f * __builtin_amdgcn_rcpf(1.f + __builtin_amdgcn_exp2f(2.f * LOG2E * x));
}

// ---------------------------------------------------------------------------
// Pre-pass: emb->bf16 (big, own kernel)
// ---------------------------------------------------------------------------
__global__ void convemb_kernel(const float* __restrict__ src, bf16* __restrict__ dst, long n4)
{
    long i = (long)blockIdx.x * 256 + threadIdx.x;
    if (i >= n4) return;
    float4 v = *(const float4*)(src + i * 4);
    *(uint2*)(dst + i * 4) = make_uint2(pack2(v.x, v.y), pack2(v.z, v.w));
}

// ---------------------------------------------------------------------------
// Fused weight-pack pre-pass (replaces 11 launches).  All dims hard-coded.
// ---------------------------------------------------------------------------
__global__ void pack_all_kernel(const float* __restrict__ Wq, const float* __restrict__ Wk,
                                const float* __restrict__ Wv, const float* __restrict__ Wskip,
                                const float* __restrict__ We, const float* __restrict__ W1,
                                const float* __restrict__ Wp, const float* __restrict__ W_ih,
                                const float* __restrict__ Wap, const float* __restrict__ W_hh,
                                const float* __restrict__ bq, const float* __restrict__ bk,
                                const float* __restrict__ bv, const float* __restrict__ bskip,
                                unsigned* __restrict__ qkvsP, unsigned* __restrict__ WeP,
                                unsigned* __restrict__ W1P, unsigned* __restrict__ WpP,
                                unsigned* __restrict__ WihP, unsigned* __restrict__ WapP,
                                short8* __restrict__ WhhP, float* __restrict__ bias4096)
{
    int i = blockIdx.x * 256 + threadIdx.x;
    if (i < 524288) {                       // qkvsP: 128 k2 x 4096
        int k2 = i >> 12, n = i & 4095;
        const float* s = (n < 1024) ? Wq : (n < 2048) ? Wk : (n < 3072) ? Wv : Wskip;
        int col = n & 1023;
        qkvsP[i] = pack2(s[(long)(2 * k2) * 1024 + col], s[(long)(2 * k2 + 1) * 1024 + col]);
        return;
    }
    i -= 524288;
    if (i < 131072) {                       // WeP: 128 x 1024
        int k2 = i >> 10, n = i & 1023;
        WeP[i] = pack2(We[(long)(2 * k2) * 1024 + n], We[(long)(2 * k2 + 1) * 1024 + n]);
        return;
    }
    i -= 131072;
    if (i < 131072) {                       // W1P: 512 k2 x 256
        int k2 = i >> 8, n = i & 255;
        W1P[i] = pack2(W1[(long)(2 * k2) * 256 + n], W1[(long)(2 * k2 + 1) * 256 + n]);
        return;
    }
    i -= 131072;
    if (i < 32768) {                        // WpP: 128 x 256
        int k2 = i >> 8, n = i & 255;
        WpP[i] = pack2(Wp[(long)(2 * k2) * 256 + n], Wp[(long)(2 * k2 + 1) * 256 + n]);
        return;
    }
    i -= 32768;
    if (i < 98304) {                        // WihP (transposed src [768,256]): 128 k2 x 768
        int k2 = i / 768, n = i % 768;
        WihP[i] = pack2(W_ih[(long)n * 256 + 2 * k2], W_ih[(long)n * 256 + 2 * k2 + 1]);
        return;
    }
    i -= 98304;
    if (i < 32768) {                        // WapP: 128 x 256
        int k2 = i >> 8, n = i & 255;
        WapP[i] = pack2(Wap[(long)(2 * k2) * 256 + n], Wap[(long)(2 * k2 + 1) * 256 + n]);
        return;
    }
    i -= 32768;
    if (i < 24576) {                        // WhhP MFMA B-frag stream
        int lane = i & 63, tk = (i >> 6) & 7, tile = i >> 9;
        int n = tile * 16 + (lane & 15);
        const float* wp = W_hh + (long)n * 256 + tk * 32 + (lane >> 4) * 8;
        float4 w0 = *(const float4*)wp;
        float4 w1 = *(const float4*)(wp + 4);
        U4S8 u;
        u.u = make_uint4(pack2(w0.x, w0.y), pack2(w0.z, w0.w),
                         pack2(w1.x, w1.y), pack2(w1.z, w1.w));
        WhhP[i] = u.s;
        return;
    }
    i -= 24576;
    if (i < 4096) {                         // bias4096
        int q = i >> 10, c = i & 1023;
        bias4096[i] = ((q == 0) ? bq : (q == 1) ? bk : (q == 2) ? bv : bskip)[c];
    }
}
#define PACK_ALL_TOT (524288 + 131072 + 131072 + 32768 + 98304 + 32768 + 24576 + 4096)

// ---------------------------------------------------------------------------
// MFMA GEMM: C[M,Nc] = act( gatherA[M,K](bf16) @ Bp(packed bf16) + bias )
// ---------------------------------------------------------------------------
#define TM 128
#define TN 128
#define TK 32
#define ASTR 40
#define BSTR 132

template <typename CT>
__global__ __launch_bounds__(256)
void pgemm_kernel(const bf16* __restrict__ A, const int* __restrict__ arows,
                  const unsigned* __restrict__ Bp, const float* __restrict__ bias,
                  CT* __restrict__ C, int M, int K, int Nc, int relu_out)
{
    __shared__ short    As[TM * ASTR];
    __shared__ unsigned Bs[(TK / 2) * BSTR];

    const int tid  = threadIdx.x;
    const int lane = tid & 63;
    const int wave = tid >> 6;
    const int wm = wave >> 1, wn = wave & 1;
    const int quad = lane >> 4, c16 = lane & 15;
    const long row0 = (long)blockIdx.y * TM;
    const int  col0 = blockIdx.x * TN;

    const int sm  = tid >> 1;
    const int sh  = (tid & 1) * 16;
    const int sn2 = tid & 63;
    const int skk = (tid >> 6) * 4;

    long gr_row = row0 + sm;
    if (gr_row > M - 1) gr_row = M - 1;
    long ar = arows ? (long)arows[gr_row] : gr_row;
    const short* Arow = (const short*)A + ar * K + sh;

    f32x4 acc[4][4];
    #pragma unroll
    for (int i = 0; i < 4; ++i)
        #pragma unroll
        for (int j = 0; j < 4; ++j)
            acc[i][j] = (f32x4){0.f, 0.f, 0.f, 0.f};

    for (int k0 = 0; k0 < K; k0 += TK) {
        {
            const short* p = Arow + k0;
            uint4 a = *(const uint4*)(p);
            uint4 b = *(const uint4*)(p + 8);
            *(uint4*)&As[sm * ASTR + sh]     = a;
            *(uint4*)&As[sm * ASTR + sh + 8] = b;
        }
        #pragma unroll
        for (int i = 0; i < 4; ++i) {
            int kk2 = skk + i;
            *(uint2*)&Bs[kk2 * BSTR + sn2 * 2] =
                *(const uint2*)&Bp[(long)(k0 / 2 + kk2) * Nc + col0 + sn2 * 2];
        }
        __syncthreads();

        short8 af[4];
        U4S8   bfr[4];
        #pragma unroll
        for (int mi = 0; mi < 4; ++mi) {
            int m = wm * 64 + mi * 16 + c16;
            af[mi] = *(const short8*)&As[m * ASTR + quad * 8];
        }
        #pragma unroll
        for (int ni = 0; ni < 4; ++ni) {
            int n = wn * 64 + ni * 16 + c16;
            uint4 u;
            u.x = Bs[(quad * 4 + 0) * BSTR + n];
            u.y = Bs[(quad * 4 + 1) * BSTR + n];
            u.z = Bs[(quad * 4 + 2) * BSTR + n];
            u.w = Bs[(quad * 4 + 3) * BSTR + n];
            bfr[ni].u = u;
        }
        #pragma unroll
        for (int mi = 0; mi < 4; ++mi)
            #pragma unroll
            for (int ni = 0; ni < 4; ++ni)
                acc[mi][ni] = __builtin_amdgcn_mfma_f32_16x16x32_bf16(
                    af[mi], bfr[ni].s, acc[mi][ni], 0, 0, 0);
        __syncthreads();
    }

    #pragma unroll
    for (int ni = 0; ni < 4; ++ni) {
        int col = col0 + wn * 64 + ni * 16 + c16;
        float bv = bias ? bias[col] : 0.f;
        #pragma unroll
        for (int mi = 0; mi < 4; ++mi) {
            long row = row0 + wm * 64 + mi * 16 + quad * 4;
            #pragma unroll
            for (int r = 0; r < 4; ++r) {
                if (row + r >= M) continue;
                float v = acc[mi][ni][r] + bv;
                if (relu_out) v = fmaxf(v, 0.f);
                C[(row + r) * Nc + col] = (CT)v;
            }
        }
    }
}

// ---------------------------------------------------------------------------
// CSR build
// ---------------------------------------------------------------------------
__global__ void zero_int_kernel(int* __restrict__ p, int n)
{
    int i = blockIdx.x * 256 + threadIdx.x;
    if (i < n) p[i] = 0;
}

__global__ void count_kernel(const int* __restrict__ edge_index, int b0,
                             int* __restrict__ cnt, int cE)
{
    int i = blockIdx.x * 256 + threadIdx.x;
    if (i >= cE) return;
    int bl = i / E_, ei = i % E_;
    int dst = edge_index[(long)(b0 + bl) * 2 * E_ + E_ + ei];
    atomicAdd(&cnt[bl * N_ + dst], 1);
}

__global__ __launch_bounds__(1024)
void scan_kernel(const int* __restrict__ cnt, int* __restrict__ row_start,
                 int* __restrict__ cursor)
{
    int bl = blockIdx.x;
    int tid = threadIdx.x;
    __shared__ int s[1024];
    int v = (tid < N_) ? cnt[bl * N_ + tid] : 0;
    s[tid] = v;
    __syncthreads();
    for (int off = 1; off < 1024; off <<= 1) {
        int t = (tid >= off) ? s[tid - off] : 0;
        __syncthreads();
        s[tid] += t;
        __syncthreads();
    }
    if (tid < N_) {
        int excl = s[tid] - v;
        row_start[bl * N_ + tid] = excl;
        cursor[bl * N_ + tid] = excl;
    }
}

__global__ void scatter_kernel(const int* __restrict__ edge_index, int b0,
                               int* __restrict__ cursor, int* __restrict__ elist, int cE)
{
    int i = blockIdx.x * 256 + threadIdx.x;
    if (i >= cE) return;
    int bl = i / E_, ei = i % E_;
    int dst = edge_index[(long)(b0 + bl) * 2 * E_ + E_ + ei];
    int pos = atomicAdd(&cursor[bl * N_ + dst], 1);
    elist[bl * E_ + pos] = ei;
}

// ---------------------------------------------------------------------------
// alpha_ex on fused qkvs buffer (stride 4096: q@0, k@1024, v@2048, skip@3072)
// ---------------------------------------------------------------------------
__device__ __forceinline__ float qke2(unsigned q, unsigned k, unsigned e)
{
    return bflo(q) * (bflo(k) + bflo(e)) + bfhi(q) * (bfhi(k) + bfhi(e));
}

__global__ void alpha_ex_kernel(const bf16* __restrict__ qkvs, const bf16* __restrict__ e,
                                const int* __restrict__ edge_index,
                                int b0, float* __restrict__ ex, int cE)
{
    int eidx = blockIdx.x * 4 + (threadIdx.x >> 6);
    int l = threadIdx.x & 63;
    int bl = eidx / E_, ei = eidx % E_;
    const int* eb = edge_index + (long)(b0 + bl) * 2 * E_;
    int src = eb[ei], dst = eb[E_ + ei];
    int head = l >> 4;
    int j0 = head * 256 + (l & 15) * 16;

    const uint4* qp = (const uint4*)(qkvs + (long)(bl * N_ + dst) * 4096 + j0);
    const uint4* kp = (const uint4*)(qkvs + (long)(bl * N_ + src) * 4096 + 1024 + j0);
    const uint4* ep = (const uint4*)(e + (long)eidx * HD_ + j0);

    uint4 qa = qp[0], qb2 = qp[1];
    uint4 ka = kp[0], kb2 = kp[1];
    uint4 ea = ep[0], eb2 = ep[1];

    float s = qke2(qa.x, ka.x, ea.x) + qke2(qa.y, ka.y, ea.y)
            + qke2(qa.z, ka.z, ea.z) + qke2(qa.w, ka.w, ea.w)
            + qke2(qb2.x, kb2.x, eb2.x) + qke2(qb2.y, kb2.y, eb2.y)
            + qke2(qb2.z, kb2.z, eb2.z) + qke2(qb2.w, kb2.w, eb2.w);

    s += __shfl_down(s, 8);
    s += __shfl_down(s, 4);
    s += __shfl_down(s, 2);
    s += __shfl_down(s, 1);

    if ((l & 15) == 0)
        ex[(long)head * cE + eidx] = expf(s * SCALE_);
}

// ---------------------------------------------------------------------------
// agg_node: CSR reduce + normalize + skip + ReLU -> bf16
// ---------------------------------------------------------------------------
__global__ void agg_node_kernel(const bf16* __restrict__ qkvs, const bf16* __restrict__ e,
                                const float* __restrict__ ex, const int* __restrict__ edge_index,
                                const int* __restrict__ row_start, const int* __restrict__ cnt,
                                const int* __restrict__ elist,
                                int b0, int cE, bf16* __restrict__ aggb)
{
    int base = blockIdx.x;
    int bl = base / N_;
    int tid = threadIdx.x;
    int h = tid >> 6;
    int j0 = tid * 4;

    int start = row_start[base];
    int deg = cnt[base];
    const int* el = elist + (long)bl * E_;
    const float* exh = ex + (long)h * cE;
    const int* srcp = edge_index + (long)(b0 + bl) * 2 * E_;

    float d = 0.f;
    for (int t = 0; t < deg; ++t)
        d += exh[(long)bl * E_ + el[start + t]];
    float invd = (deg > 0) ? 1.f / d : 0.f;

    float a0 = 0.f, a1 = 0.f, a2 = 0.f, a3 = 0.f;
    for (int t = 0; t < deg; ++t) {
        int ei = el[start + t];
        long eidx = (long)bl * E_ + ei;
        float w = exh[eidx] * invd;
        int src = srcp[ei];
        uint2 vv = *(const uint2*)(qkvs + (long)(bl * N_ + src) * 4096 + 2048 + j0);
        uint2 ee = *(const uint2*)(e + eidx * HD_ + j0);
        a0 += w * (bflo(vv.x) + bflo(ee.x));
        a1 += w * (bfhi(vv.x) + bfhi(ee.x));
        a2 += w * (bflo(vv.y) + bflo(ee.y));
        a3 += w * (bfhi(vv.y) + bfhi(ee.y));
    }

    uint2 sk = *(const uint2*)(qkvs + (long)base * 4096 + 3072 + j0);
    unsigned o0 = pack2(fmaxf(bflo(sk.x) + a0, 0.f), fmaxf(bfhi(sk.x) + a1, 0.f));
    unsigned o1 = pack2(fmaxf(bflo(sk.y) + a2, 0.f), fmaxf(bfhi(sk.y) + a3, 0.f));
    *(uint2*)(aggb + (long)base * HD_ + j0) = make_uint2(o0, o1);
}

// ---------------------------------------------------------------------------
// fused mixed embed (inv rows then aa rows) -> bf16
// ---------------------------------------------------------------------------
__global__ void mixed2_kernel(const bf16* __restrict__ embh,
                              const int* __restrict__ inv_token, const int* __restrict__ inv_node,
                              const int* __restrict__ aa_token, const int* __restrict__ aa_node,
                              const float* __restrict__ graph_repr,
                              bf16* __restrict__ mixed_inv, bf16* __restrict__ aa_emb)
{
    int r = blockIdx.x;
    int d = threadIdx.x;
    if (r < B_ * L_) {
        int b = r / L_;
        float v = (float)embh[(long)inv_token[r] * D_ + d] +
                  graph_repr[((long)b * N_ + inv_node[r]) * D_ + d];
        mixed_inv[(long)r * D_ + d] = __float2bfloat16(v);
    } else {
        int r2 = r - B_ * L_;
        int b = r2 / A_;
        float v = (float)embh[(long)aa_token[r2] * D_ + d] +
                  graph_repr[((long)b * N_ + aa_node[r2]) * D_ + d];
        aa_emb[(long)r2 * D_ + d] = __float2bfloat16(v);
    }
}

// ---------------------------------------------------------------------------
// GRU via MFMA: one block, 16 waves.  3 n-tiles/wave register-resident.
// Cheap activations (v_exp2 + v_rcp), fast RNE pack, gx prefetched one step
// ahead via static register rotation (no indexed arrays -> no scratch).
// ---------------------------------------------------------------------------
#define GSTR 780

__global__ __launch_bounds__(1024)
void gru_kernel(const bf16* __restrict__ gxh, const short8* __restrict__ WhhP,
                const float* __restrict__ b_hh, float* __restrict__ inv_out)
{
    __shared__ float gatesLDS[16 * GSTR];   // 49920 B
    __shared__ short hB[16 * 264];          // 8448 B

    const int tid = threadIdx.x;
    const int lane = tid & 63;
    const int wave = tid >> 6;              // 0..15
    const int quad = lane >> 4, col = lane & 15;

    for (int i = tid; i < 16 * 264; i += 1024) hB[i] = 0;

    short8 wfrag[3][8];
    float bhh[3];
    #pragma unroll
    for (int i = 0; i < 3; ++i) {
        int tile = wave * 3 + i;
        bhh[i] = b_hh[tile * 16 + col];
        #pragma unroll
        for (int tk = 0; tk < 8; ++tk)
            wfrag[i][tk] = WhhP[(tile * 8 + tk) * 64 + lane];
    }

    const int em = tid >> 6;
    const int c0 = (tid & 63) * 4;
    float myh0 = 0.f, myh1 = 0.f, myh2 = 0.f, myh3 = 0.f;

    const short* gbase = (const short*)gxh + (long)em * L_ * 768 + c0;

    // prefetch t=0
    uint2 pxr = *(const uint2*)(gbase);
    uint2 pxz = *(const uint2*)(gbase + 256);
    uint2 pxn = *(const uint2*)(gbase + 512);

    __syncthreads();

    for (int t = 0; t < L_; ++t) {
        uint2 xr2 = pxr, xz2 = pxz, xn2 = pxn;
        // prefetch t+1 (hidden behind the MFMA phase)
        int nxt = (t + 1 < L_) ? t + 1 : t;
        const short* gp = gbase + (long)nxt * 768;
        pxr = *(const uint2*)(gp);
        pxz = *(const uint2*)(gp + 256);
        pxn = *(const uint2*)(gp + 512);

        // MFMA: gates = h @ W_hh^T + b_hh
        f32x4 acc0 = (f32x4){bhh[0], bhh[0], bhh[0], bhh[0]};
        f32x4 acc1 = (f32x4){bhh[1], bhh[1], bhh[1], bhh[1]};
        f32x4 acc2 = (f32x4){bhh[2], bhh[2], bhh[2], bhh[2]};
        #pragma unroll
        for (int tk = 0; tk < 8; ++tk) {
            short8 a = *(const short8*)&hB[col * 264 + tk * 32 + quad * 8];
            acc0 = __builtin_amdgcn_mfma_f32_16x16x32_bf16(a, wfrag[0][tk], acc0, 0, 0, 0);
            acc1 = __builtin_amdgcn_mfma_f32_16x16x32_bf16(a, wfrag[1][tk], acc1, 0, 0, 0);
            acc2 = __builtin_amdgcn_mfma_f32_16x16x32_bf16(a, wfrag[2][tk], acc2, 0, 0, 0);
        }
        #pragma unroll
        for (int r = 0; r < 4; ++r) {
            int m = quad * 4 + r;
            gatesLDS[m * GSTR + (wave * 3 + 0) * 16 + col] = acc0[r];
            gatesLDS[m * GSTR + (wave * 3 + 1) * 16 + col] = acc1[r];
            gatesLDS[m * GSTR + (wave * 3 + 2) * 16 + col] = acc2[r];
        }
        __syncthreads();

        // elementwise
        const float* g = &gatesLDS[em * GSTR + c0];
        float4 grv = *(const float4*)(g);
        float4 gzv = *(const float4*)(g + 256);
        float4 gnv = *(const float4*)(g + 512);
        float gr[4] = {grv.x, grv.y, grv.z, grv.w};
        float gz[4] = {gzv.x, gzv.y, gzv.z, gzv.w};
        float gn[4] = {gnv.x, gnv.y, gnv.z, gnv.w};
        float xr[4] = {bflo(xr2.x), bfhi(xr2.x), bflo(xr2.y), bfhi(xr2.y)};
        float xz[4] = {bflo(xz2.x), bfhi(xz2.x), bflo(xz2.y), bfhi(xz2.y)};
        float xn[4] = {bflo(xn2.x), bfhi(xn2.x), bflo(xn2.y), bfhi(xn2.y)};
        float hn[4];
        float hold[4] = {myh0, myh1, myh2, myh3};
        #pragma unroll
        for (int j = 0; j < 4; ++j) {
            float r = fsigm(xr[j] + gr[j]);
            float z = fsigm(xz[j] + gz[j]);
            float cc = ftanh(xn[j] + r * gn[j]);
            hn[j] = (1.f - z) * cc + z * hold[j];
        }
        myh0 = hn[0]; myh1 = hn[1]; myh2 = hn[2]; myh3 = hn[3];
        *(uint2*)&hB[em * 264 + c0] =
            make_uint2(rne2(hn[0], hn[1]), rne2(hn[2], hn[3]));
        __syncthreads();
    }

    float* op = inv_out + (long)em * 256 + c0;
    *(float4*)op = make_float4(myh0, myh1, myh2, myh3);
}

// ---------------------------------------------------------------------------
// scores (aa_emb bf16, aa_p f32)
// ---------------------------------------------------------------------------
__global__ void score_kernel(const float* __restrict__ aa_p, const bf16* __restrict__ aa_emb,
                             const float* __restrict__ inv, const float* __restrict__ Wab,
                             const float* __restrict__ bab, const float* __restrict__ mask,
                             float* __restrict__ out)
{
    int r = blockIdx.x * 4 + (threadIdx.x >> 6);
    int l = threadIdx.x & 63;
    int b = r / A_;
    float s = 0.f;
    for (int d = l; d < D_; d += 64)
        s += aa_p[(long)r * D_ + d] * inv[(long)b * D_ + d] +
             (float)aa_emb[(long)r * D_ + d] * Wab[d];
    #pragma unroll
    for (int off = 32; off; off >>= 1) s += __shfl_down(s, off);
    if (l == 0) {
        float lm = logf(mask[r]);
        const float MN = -3.4028234663852886e38f;
        if (!(lm >= MN)) lm = MN;
        out[r] = s + bab[0] + lm;
    }
}

// ---------------------------------------------------------------------------
// host
// ---------------------------------------------------------------------------
static inline size_t align256(size_t x) { return (x + 255) & ~(size_t)255; }

template <typename CT>
static void launch_pgemm(const bf16* A, const int* arows, const unsigned* Bp,
                         const float* bias, CT* C, int M, int K, int Nc, int relu,
                         hipStream_t s)
{
    dim3 grid(Nc / TN, (M + TM - 1) / TM);
    pgemm_kernel<CT><<<grid, 256, 0, s>>>(A, arows, Bp, bias, C, M, K, Nc, relu);
}

extern "C" void kernel_launch(void* const* d_in, const int* in_sizes, int n_in,
                              void* d_out, int out_size, void* d_ws, size_t ws_size,
                              hipStream_t stream)
{
    const int* node_tokens = (const int*)d_in[0];
    const int* edge_tokens = (const int*)d_in[1];
    const int* edge_index  = (const int*)d_in[2];
    const int* inv_token   = (const int*)d_in[3];
    const int* inv_node    = (const int*)d_in[4];
    const int* aa_token    = (const int*)d_in[5];
    const int* aa_node     = (const int*)d_in[6];
    const float* action_mask = (const float*)d_in[7];
    const float* emb   = (const float*)d_in[8];
    const float* Wq    = (const float*)d_in[9];
    const float* bq    = (const float*)d_in[10];
    const float* Wk    = (const float*)d_in[11];
    const float* bk    = (const float*)d_in[12];
    const float* Wv    = (const float*)d_in[13];
    const float* bv    = (const float*)d_in[14];
    const float* We    = (const float*)d_in[15];
    const float* Wskip = (const float*)d_in[16];
    const float* bskip = (const float*)d_in[17];
    const float* W1    = (const float*)d_in[18];
    const float* b1    = (const float*)d_in[19];
    const float* Wp    = (const float*)d_in[20];
    const float* bp    = (const float*)d_in[21];
    const float* W_ih  = (const float*)d_in[22];
    const float* W_hh  = (const float*)d_in[23];
    const float* b_ih  = (const float*)d_in[24];
    const float* b_hh  = (const float*)d_in[25];
    const float* Wab   = (const float*)d_in[26];
    const float* bab   = (const float*)d_in[27];
    const float* Wap   = (const float*)d_in[28];
    const float* bap   = (const float*)d_in[29];
    (void)in_sizes; (void)n_in; (void)out_size;

    char* base = (char*)d_ws;
    size_t off = 0;
    auto alloc = [&](size_t bytes) -> char* {
        char* p = base + off;
        off = align256(off + bytes);
        return p;
    };

    // persistent buffers
    const long VD = 50000L * 256;
    bf16*  embh       = (bf16*)alloc(VD * 2);
    float* graph_repr = (float*)alloc((size_t)B_ * N_ * D_ * 4);
    bf16*  mixed_inv  = (bf16*)alloc((size_t)B_ * L_ * D_ * 2);
    bf16*  inv_h      = (bf16*)alloc((size_t)B_ * L_ * D_ * 2);
    bf16*  gxh        = (bf16*)alloc((size_t)B_ * L_ * 768 * 2);
    float* inv_out    = (float*)alloc((size_t)B_ * 256 * 4);
    bf16*  aa_emb     = (bf16*)alloc((size_t)B_ * A_ * D_ * 2);
    float* aa_p       = (float*)alloc((size_t)B_ * A_ * 256 * 4);
    unsigned* qkvsP   = (unsigned*)alloc((size_t)128 * 4096 * 4);
    unsigned* WeP     = (unsigned*)alloc((size_t)128 * 1024 * 4);
    unsigned* W1P     = (unsigned*)alloc((size_t)512 * 256 * 4);
    unsigned* WpP     = (unsigned*)alloc((size_t)128 * 256 * 4);
    unsigned* WihP    = (unsigned*)alloc((size_t)128 * 768 * 4);
    unsigned* WapP    = (unsigned*)alloc((size_t)128 * 256 * 4);
    short8* WhhP      = (short8*)alloc((size_t)24576 * 16);
    float* bias4096   = (float*)alloc(4096 * 4);
    size_t persist = off;

    // batch-chunk size
    int c = 16;
    while (c > 1) {
        size_t cN = (size_t)c * N_, cEs = (size_t)c * E_;
        size_t chunk = align256(cN * 4096 * 2)
                     + align256(cEs * HD_ * 2)
                     + align256(cN * HD_ * 2)
                     + align256(cEs * H_ * 4)
                     + 3 * align256(cN * 4)
                     + align256(cEs * 4);
        if (persist + chunk <= ws_size) break;
        c >>= 1;
    }
    int cN = c * N_, cE = c * E_;

    bf16*  qkvs  = (bf16*)alloc((size_t)cN * 4096 * 2);
    bf16*  ebuf  = (bf16*)alloc((size_t)cE * HD_ * 2);
    bf16*  aggb  = (bf16*)alloc((size_t)cN * HD_ * 2);
    float* ex    = (float*)alloc((size_t)cE * H_ * 4);
    int*   cnt   = (int*)alloc((size_t)cN * 4);
    int*   rstart= (int*)alloc((size_t)cN * 4);
    int*   cursor= (int*)alloc((size_t)cN * 4);
    int*   elist = (int*)alloc((size_t)cE * 4);

    // ---- pre-pass (2 launches) ----
    convemb_kernel<<<(int)((VD / 4 + 255) / 256), 256, 0, stream>>>(emb, embh, VD / 4);
    pack_all_kernel<<<(PACK_ALL_TOT + 255) / 256, 256, 0, stream>>>(
        Wq, Wk, Wv, Wskip, We, W1, Wp, W_ih, Wap, W_hh, bq, bk, bv, bskip,
        qkvsP, WeP, W1P, WpP, WihP, WapP, WhhP, bias4096);

    for (int b0 = 0; b0 < B_; b0 += c) {
        // CSR
        zero_int_kernel<<<(cN + 255) / 256, 256, 0, stream>>>(cnt, cN);
        count_kernel<<<(cE + 255) / 256, 256, 0, stream>>>(edge_index, b0, cnt, cE);
        scan_kernel<<<c, 1024, 0, stream>>>(cnt, rstart, cursor);
        scatter_kernel<<<(cE + 255) / 256, 256, 0, stream>>>(edge_index, b0, cursor,
                                                             elist, cE);
        // fused q|k|v|skip projection + edge projection
        launch_pgemm<bf16>(embh, node_tokens + (long)b0 * N_, qkvsP, bias4096, qkvs,
                           cN, D_, 4096, 0, stream);
        launch_pgemm<bf16>(embh, edge_tokens + (long)b0 * E_, WeP, nullptr, ebuf,
                           cE, D_, HD_, 0, stream);
        // attention
        alpha_ex_kernel<<<cE / 4, 256, 0, stream>>>(qkvs, ebuf, edge_index, b0, ex, cE);
        agg_node_kernel<<<cN, 256, 0, stream>>>(qkvs, ebuf, ex, edge_index, rstart, cnt,
                                                elist, b0, cE, aggb);
        // graph_repr = relu(aggb @ W1 + b1)
        launch_pgemm<float>(aggb, nullptr, W1P, b1,
                            graph_repr + (long)b0 * N_ * D_, cN, HD_, D_, 1, stream);
    }

    // invariant + action embeds (fused)
    mixed2_kernel<<<B_ * L_ + B_ * A_, 256, 0, stream>>>(embh, inv_token, inv_node,
                                                         aa_token, aa_node, graph_repr,
                                                         mixed_inv, aa_emb);
    launch_pgemm<bf16>(mixed_inv, nullptr, WpP, bp, inv_h, B_ * L_, D_, 256, 1, stream);
    launch_pgemm<bf16>(inv_h, nullptr, WihP, b_ih, gxh, B_ * L_, 256, 768, 0, stream);
    gru_kernel<<<1, 1024, 0, stream>>>(gxh, WhhP, b_hh, inv_out);

    // action path
    launch_pgemm<float>(aa_emb, nullptr, WapP, bap, aa_p, B_ * A_, D_, 256, 0, stream);
    score_kernel<<<(B_ * A_) / 4, 256, 0, stream>>>(aa_p, aa_emb, inv_out, Wab, bab,
                                                    action_mask, (float*)d_out);
}

// Round 9
// 888.418 us; speedup vs baseline: 1.0740x; 1.0208x over previous
//
#include <hip/hip_runtime.h>
#include <hip/hip_bf16.h>
#include <float.h>
#include <math.h>

typedef __hip_bfloat16 bf16;

#define B_ 16
#define N_ 1000
#define E_ 4000
#define L_ 64
#define A_ 128
#define D_ 256
#define H_ 4
#define HD_ 1024
#define SCALE_ 0.0625f

typedef __attribute__((ext_vector_type(8))) short short8;
typedef __attribute__((ext_vector_type(4))) float f32x4;

union U4S8 { uint4 u; short8 s; };

__device__ __forceinline__ unsigned short f2bf(float f) {
    bf16 h = __float2bfloat16(f);
    return *reinterpret_cast<unsigned short*>(&h);
}
__device__ __forceinline__ unsigned pack2(float a, float b) {
    return (unsigned)f2bf(a) | ((unsigned)f2bf(b) << 16);
}
__device__ __forceinline__ unsigned short rne1(float a) {
    unsigned ua = __float_as_uint(a);
    ua += 0x7fff + ((ua >> 16) & 1);
    return (unsigned short)(ua >> 16);
}
__device__ __forceinline__ float bflo(unsigned u) { return __uint_as_float(u << 16); }
__device__ __forceinline__ float bfhi(unsigned u) { return __uint_as_float(u & 0xffff0000u); }

#define LOG2E 1.4426950408889634f
__device__ __forceinline__ float fsigm(float x) {
    return __builtin_amdgcn_rcpf(1.f + __builtin_amdgcn_exp2f(-LOG2E * x));
}
__device__ __forceinline__ float ftanh(float x) {
    return 1.f - 2.f * __builtin_amdgcn_rcpf(1.f + __builtin_amdgcn_exp2f(2.f * LOG2E * x));
}

// ---------------------------------------------------------------------------
// Pre-pass: emb->bf16
// ---------------------------------------------------------------------------
__global__ void convemb_kernel(const float* __restrict__ src, bf16* __restrict__ dst, long n4)
{
    long i = (long)blockIdx.x * 256 + threadIdx.x;
    if (i >= n4) return;
    float4 v = *(const float4*)(src + i * 4);
    *(uint2*)(dst + i * 4) = make_uint2(pack2(v.x, v.y), pack2(v.z, v.w));
}

// ---------------------------------------------------------------------------
// Fused weight-pack pre-pass
// ---------------------------------------------------------------------------
__global__ void pack_all_kernel(const float* __restrict__ Wq, const float* __restrict__ Wk,
                                const float* __restrict__ Wv, const float* __restrict__ Wskip,
                                const float* __restrict__ We, const float* __restrict__ W1,
                                const float* __restrict__ Wp, const float* __restrict__ W_ih,
                                const float* __restrict__ Wap, const float* __restrict__ W_hh,
                                const float* __restrict__ bq, const float* __restrict__ bk,
                                const float* __restrict__ bv, const float* __restrict__ bskip,
                                unsigned* __restrict__ qkvsP, unsigned* __restrict__ WeP,
                                unsigned* __restrict__ W1P, unsigned* __restrict__ WpP,
                                unsigned* __restrict__ WihP, unsigned* __restrict__ WapP,
                                short8* __restrict__ WhhP, float* __restrict__ bias4096)
{
    int i = blockIdx.x * 256 + threadIdx.x;
    if (i < 524288) {                       // qkvsP: 128 k2 x 4096
        int k2 = i >> 12, n = i & 4095;
        const float* s = (n < 1024) ? Wq : (n < 2048) ? Wk : (n < 3072) ? Wv : Wskip;
        int col = n & 1023;
        qkvsP[i] = pack2(s[(long)(2 * k2) * 1024 + col], s[(long)(2 * k2 + 1) * 1024 + col]);
        return;
    }
    i -= 524288;
    if (i < 131072) {                       // WeP: 128 x 1024
        int k2 = i >> 10, n = i & 1023;
        WeP[i] = pack2(We[(long)(2 * k2) * 1024 + n], We[(long)(2 * k2 + 1) * 1024 + n]);
        return;
    }
    i -= 131072;
    if (i < 131072) {                       // W1P: 512 k2 x 256
        int k2 = i >> 8, n = i & 255;
        W1P[i] = pack2(W1[(long)(2 * k2) * 256 + n], W1[(long)(2 * k2 + 1) * 256 + n]);
        return;
    }
    i -= 131072;
    if (i < 32768) {                        // WpP: 128 x 256
        int k2 = i >> 8, n = i & 255;
        WpP[i] = pack2(Wp[(long)(2 * k2) * 256 + n], Wp[(long)(2 * k2 + 1) * 256 + n]);
        return;
    }
    i -= 32768;
    if (i < 98304) {                        // WihP (transposed src [768,256]): 128 k2 x 768
        int k2 = i / 768, n = i % 768;
        WihP[i] = pack2(W_ih[(long)n * 256 + 2 * k2], W_ih[(long)n * 256 + 2 * k2 + 1]);
        return;
    }
    i -= 98304;
    if (i < 32768) {                        // WapP: 128 x 256
        int k2 = i >> 8, n = i & 255;
        WapP[i] = pack2(Wap[(long)(2 * k2) * 256 + n], Wap[(long)(2 * k2 + 1) * 256 + n]);
        return;
    }
    i -= 32768;
    if (i < 24576) {                        // WhhP MFMA B-frag stream (48 tiles)
        int lane = i & 63, tk = (i >> 6) & 7, tile = i >> 9;
        int n = tile * 16 + (lane & 15);
        const float* wp = W_hh + (long)n * 256 + tk * 32 + (lane >> 4) * 8;
        float4 w0 = *(const float4*)wp;
        float4 w1 = *(const float4*)(wp + 4);
        U4S8 u;
        u.u = make_uint4(pack2(w0.x, w0.y), pack2(w0.z, w0.w),
                         pack2(w1.x, w1.y), pack2(w1.z, w1.w));
        WhhP[i] = u.s;
        return;
    }
    i -= 24576;
    if (i < 4096) {                         // bias4096
        int q = i >> 10, c = i & 1023;
        bias4096[i] = ((q == 0) ? bq : (q == 1) ? bk : (q == 2) ? bv : bskip)[c];
    }
}
#define PACK_ALL_TOT (524288 + 131072 + 131072 + 32768 + 98304 + 32768 + 24576 + 4096)

// ---------------------------------------------------------------------------
// gx transpose: gxh[B*L][768] -> gxT[t][768][16 batches]  (bf16)
// ---------------------------------------------------------------------------
__global__ void gxt_kernel(const bf16* __restrict__ gxh, bf16* __restrict__ gxT)
{
    int i = blockIdx.x * 256 + threadIdx.x;      // B*L*768 = 786432
    if (i >= B_ * L_ * 768) return;
    int b = i / (L_ * 768);
    int rem = i - b * (L_ * 768);
    int t = rem / 768, n = rem - (rem / 768) * 768;
    gxT[((long)t * 768 + n) * 16 + b] = gxh[i];
}

// ---------------------------------------------------------------------------
// MFMA GEMM: C[M,Nc] = act( gatherA[M,K](bf16) @ Bp(packed bf16) + bias )
// ---------------------------------------------------------------------------
#define TM 128
#define TN 128
#define TK 32
#define ASTR 40
#define BSTR 132

template <typename CT>
__global__ __launch_bounds__(256)
void pgemm_kernel(const bf16* __restrict__ A, const int* __restrict__ arows,
                  const unsigned* __restrict__ Bp, const float* __restrict__ bias,
                  CT* __restrict__ C, int M, int K, int Nc, int relu_out)
{
    __shared__ short    As[TM * ASTR];
    __shared__ unsigned Bs[(TK / 2) * BSTR];

    const int tid  = threadIdx.x;
    const int lane = tid & 63;
    const int wave = tid >> 6;
    const int wm = wave >> 1, wn = wave & 1;
    const int quad = lane >> 4, c16 = lane & 15;
    const long row0 = (long)blockIdx.y * TM;
    const int  col0 = blockIdx.x * TN;

    const int sm  = tid >> 1;
    const int sh  = (tid & 1) * 16;
    const int sn2 = tid & 63;
    const int skk = (tid >> 6) * 4;

    long gr_row = row0 + sm;
    if (gr_row > M - 1) gr_row = M - 1;
    long ar = arows ? (long)arows[gr_row] : gr_row;
    const short* Arow = (const short*)A + ar * K + sh;

    f32x4 acc[4][4];
    #pragma unroll
    for (int i = 0; i < 4; ++i)
        #pragma unroll
        for (int j = 0; j < 4; ++j)
            acc[i][j] = (f32x4){0.f, 0.f, 0.f, 0.f};

    for (int k0 = 0; k0 < K; k0 += TK) {
        {
            const short* p = Arow + k0;
            uint4 a = *(const uint4*)(p);
            uint4 b = *(const uint4*)(p + 8);
            *(uint4*)&As[sm * ASTR + sh]     = a;
            *(uint4*)&As[sm * ASTR + sh + 8] = b;
        }
        #pragma unroll
        for (int i = 0; i < 4; ++i) {
            int kk2 = skk + i;
            *(uint2*)&Bs[kk2 * BSTR + sn2 * 2] =
                *(const uint2*)&Bp[(long)(k0 / 2 + kk2) * Nc + col0 + sn2 * 2];
        }
        __syncthreads();

        short8 af[4];
        U4S8   bfr[4];
        #pragma unroll
        for (int mi = 0; mi < 4; ++mi) {
            int m = wm * 64 + mi * 16 + c16;
            af[mi] = *(const short8*)&As[m * ASTR + quad * 8];
        }
        #pragma unroll
        for (int ni = 0; ni < 4; ++ni) {
            int n = wn * 64 + ni * 16 + c16;
            uint4 u;
            u.x = Bs[(quad * 4 + 0) * BSTR + n];
            u.y = Bs[(quad * 4 + 1) * BSTR + n];
            u.z = Bs[(quad * 4 + 2) * BSTR + n];
            u.w = Bs[(quad * 4 + 3) * BSTR + n];
            bfr[ni].u = u;
        }
        #pragma unroll
        for (int mi = 0; mi < 4; ++mi)
            #pragma unroll
            for (int ni = 0; ni < 4; ++ni)
                acc[mi][ni] = __builtin_amdgcn_mfma_f32_16x16x32_bf16(
                    af[mi], bfr[ni].s, acc[mi][ni], 0, 0, 0);
        __syncthreads();
    }

    #pragma unroll
    for (int ni = 0; ni < 4; ++ni) {
        int col = col0 + wn * 64 + ni * 16 + c16;
        float bv = bias ? bias[col] : 0.f;
        #pragma unroll
        for (int mi = 0; mi < 4; ++mi) {
            long row = row0 + wm * 64 + mi * 16 + quad * 4;
            #pragma unroll
            for (int r = 0; r < 4; ++r) {
                if (row + r >= M) continue;
                float v = acc[mi][ni][r] + bv;
                if (relu_out) v = fmaxf(v, 0.f);
                C[(row + r) * Nc + col] = (CT)v;
            }
        }
    }
}

// ---------------------------------------------------------------------------
// CSR build
// ---------------------------------------------------------------------------
__global__ void zero_int_kernel(int* __restrict__ p, int n)
{
    int i = blockIdx.x * 256 + threadIdx.x;
    if (i < n) p[i] = 0;
}

__global__ void count_kernel(const int* __restrict__ edge_index, int b0,
                             int* __restrict__ cnt, int cE)
{
    int i = blockIdx.x * 256 + threadIdx.x;
    if (i >= cE) return;
    int bl = i / E_, ei = i % E_;
    int dst = edge_index[(long)(b0 + bl) * 2 * E_ + E_ + ei];
    atomicAdd(&cnt[bl * N_ + dst], 1);
}

__global__ __launch_bounds__(1024)
void scan_kernel(const int* __restrict__ cnt, int* __restrict__ row_start,
                 int* __restrict__ cursor)
{
    int bl = blockIdx.x;
    int tid = threadIdx.x;
    __shared__ int s[1024];
    int v = (tid < N_) ? cnt[bl * N_ + tid] : 0;
    s[tid] = v;
    __syncthreads();
    for (int off = 1; off < 1024; off <<= 1) {
        int t = (tid >= off) ? s[tid - off] : 0;
        __syncthreads();
        s[tid] += t;
        __syncthreads();
    }
    if (tid < N_) {
        int excl = s[tid] - v;
        row_start[bl * N_ + tid] = excl;
        cursor[bl * N_ + tid] = excl;
    }
}

__global__ void scatter_kernel(const int* __restrict__ edge_index, int b0,
                               int* __restrict__ cursor, int* __restrict__ elist, int cE)
{
    int i = blockIdx.x * 256 + threadIdx.x;
    if (i >= cE) return;
    int bl = i / E_, ei = i % E_;
    int dst = edge_index[(long)(b0 + bl) * 2 * E_ + E_ + ei];
    int pos = atomicAdd(&cursor[bl * N_ + dst], 1);
    elist[bl * E_ + pos] = ei;
}

// ---------------------------------------------------------------------------
// alpha_ex on fused qkvs buffer (stride 4096: q@0, k@1024, v@2048, skip@3072)
// ---------------------------------------------------------------------------
__device__ __forceinline__ float qke2(unsigned q, unsigned k, unsigned e)
{
    return bflo(q) * (bflo(k) + bflo(e)) + bfhi(q) * (bfhi(k) + bfhi(e));
}

__global__ void alpha_ex_kernel(const bf16* __restrict__ qkvs, const bf16* __restrict__ e,
                                const int* __restrict__ edge_index,
                                int b0, float* __restrict__ ex, int cE)
{
    int eidx = blockIdx.x * 4 + (threadIdx.x >> 6);
    int l = threadIdx.x & 63;
    int bl = eidx / E_, ei = eidx % E_;
    const int* eb = edge_index + (long)(b0 + bl) * 2 * E_;
    int src = eb[ei], dst = eb[E_ + ei];
    int head = l >> 4;
    int j0 = head * 256 + (l & 15) * 16;

    const uint4* qp = (const uint4*)(qkvs + (long)(bl * N_ + dst) * 4096 + j0);
    const uint4* kp = (const uint4*)(qkvs + (long)(bl * N_ + src) * 4096 + 1024 + j0);
    const uint4* ep = (const uint4*)(e + (long)eidx * HD_ + j0);

    uint4 qa = qp[0], qb2 = qp[1];
    uint4 ka = kp[0], kb2 = kp[1];
    uint4 ea = ep[0], eb2 = ep[1];

    float s = qke2(qa.x, ka.x, ea.x) + qke2(qa.y, ka.y, ea.y)
            + qke2(qa.z, ka.z, ea.z) + qke2(qa.w, ka.w, ea.w)
            + qke2(qb2.x, kb2.x, eb2.x) + qke2(qb2.y, kb2.y, eb2.y)
            + qke2(qb2.z, kb2.z, eb2.z) + qke2(qb2.w, kb2.w, eb2.w);

    s += __shfl_down(s, 8);
    s += __shfl_down(s, 4);
    s += __shfl_down(s, 2);
    s += __shfl_down(s, 1);

    if ((l & 15) == 0)
        ex[(long)head * cE + eidx] = __builtin_amdgcn_exp2f(s * (SCALE_ * LOG2E));
}

// ---------------------------------------------------------------------------
// agg_node: CSR reduce + normalize + skip + ReLU -> bf16
// ---------------------------------------------------------------------------
__global__ void agg_node_kernel(const bf16* __restrict__ qkvs, const bf16* __restrict__ e,
                                const float* __restrict__ ex, const int* __restrict__ edge_index,
                                const int* __restrict__ row_start, const int* __restrict__ cnt,
                                const int* __restrict__ elist,
                                int b0, int cE, bf16* __restrict__ aggb)
{
    int base = blockIdx.x;
    int bl = base / N_;
    int tid = threadIdx.x;
    int h = tid >> 6;
    int j0 = tid * 4;

    int start = row_start[base];
    int deg = cnt[base];
    const int* el = elist + (long)bl * E_;
    const float* exh = ex + (long)h * cE;
    const int* srcp = edge_index + (long)(b0 + bl) * 2 * E_;

    float d = 0.f;
    for (int t = 0; t < deg; ++t)
        d += exh[(long)bl * E_ + el[start + t]];
    float invd = (deg > 0) ? 1.f / d : 0.f;

    float a0 = 0.f, a1 = 0.f, a2 = 0.f, a3 = 0.f;
    for (int t = 0; t < deg; ++t) {
        int ei = el[start + t];
        long eidx = (long)bl * E_ + ei;
        float w = exh[eidx] * invd;
        int src = srcp[ei];
        uint2 vv = *(const uint2*)(qkvs + (long)(bl * N_ + src) * 4096 + 2048 + j0);
        uint2 ee = *(const uint2*)(e + eidx * HD_ + j0);
        a0 += w * (bflo(vv.x) + bflo(ee.x));
        a1 += w * (bfhi(vv.x) + bfhi(ee.x));
        a2 += w * (bflo(vv.y) + bflo(ee.y));
        a3 += w * (bfhi(vv.y) + bfhi(ee.y));
    }

    uint2 sk = *(const uint2*)(qkvs + (long)base * 4096 + 3072 + j0);
    unsigned o0 = pack2(fmaxf(bflo(sk.x) + a0, 0.f), fmaxf(bfhi(sk.x) + a1, 0.f));
    unsigned o1 = pack2(fmaxf(bflo(sk.y) + a2, 0.f), fmaxf(bfhi(sk.y) + a3, 0.f));
    *(uint2*)(aggb + (long)base * HD_ + j0) = make_uint2(o0, o1);
}

// ---------------------------------------------------------------------------
// fused mixed embed (inv rows then aa rows) -> bf16
// ---------------------------------------------------------------------------
__global__ void mixed2_kernel(const bf16* __restrict__ embh,
                              const int* __restrict__ inv_token, const int* __restrict__ inv_node,
                              const int* __restrict__ aa_token, const int* __restrict__ aa_node,
                              const float* __restrict__ graph_repr,
                              bf16* __restrict__ mixed_inv, bf16* __restrict__ aa_emb)
{
    int r = blockIdx.x;
    int d = threadIdx.x;
    if (r < B_ * L_) {
        int b = r / L_;
        float v = (float)embh[(long)inv_token[r] * D_ + d] +
                  graph_repr[((long)b * N_ + inv_node[r]) * D_ + d];
        mixed_inv[(long)r * D_ + d] = __float2bfloat16(v);
    } else {
        int r2 = r - B_ * L_;
        int b = r2 / A_;
        float v = (float)embh[(long)aa_token[r2] * D_ + d] +
                  graph_repr[((long)b * N_ + aa_node[r2]) * D_ + d];
        aa_emb[(long)r2 * D_ + d] = __float2bfloat16(v);
    }
}

// ---------------------------------------------------------------------------
// GRU via MFMA, gates fully in-register.  16 waves; wave w owns gate-columns
// [16w,16w+16) for r (tile w), z (tile 16+w), n (tile 32+w).  Lane's three
// accumulators hold r/z/n for the SAME (batch=quad*4+r, col) -> elementwise
// is in-register, h_old in the same lane.  h double-buffered in LDS (A-frag
// layout) -> ONE barrier per step, no gates LDS, no 8-way conflicts.
// gx pre-transposed [t][768][16], prefetched one step ahead.
// ---------------------------------------------------------------------------
__global__ __launch_bounds__(1024)
void gru_kernel(const bf16* __restrict__ gxT, const short8* __restrict__ WhhP,
                const float* __restrict__ b_hh, float* __restrict__ inv_out)
{
    __shared__ short hB[2][16 * 264];       // 16896 B

    const int tid = threadIdx.x;
    const int lane = tid & 63;
    const int wave = tid >> 6;              // 0..15
    const int quad = lane >> 4, c16 = lane & 15;
    const int n0 = wave * 16 + c16;         // hidden/col index 0..255

    for (int i = tid; i < 2 * 16 * 264; i += 1024) ((short*)hB)[i] = 0;

    short8 wfr[8], wfz[8], wfn[8];
    #pragma unroll
    for (int tk = 0; tk < 8; ++tk) {
        wfr[tk] = WhhP[((0 * 16 + wave) * 8 + tk) * 64 + lane];
        wfz[tk] = WhhP[((1 * 16 + wave) * 8 + tk) * 64 + lane];
        wfn[tk] = WhhP[((2 * 16 + wave) * 8 + tk) * 64 + lane];
    }
    float bhr = b_hh[0 * 256 + n0];
    float bhz = b_hh[1 * 256 + n0];
    float bhn = b_hh[2 * 256 + n0];

    float myh0 = 0.f, myh1 = 0.f, myh2 = 0.f, myh3 = 0.f;

    const short* gbr = (const short*)gxT + (long)(0 * 256 + n0) * 16 + quad * 4;
    const short* gbz = gbr + 256 * 16;
    const short* gbn = gbr + 512 * 16;

    uint2 pxr = *(const uint2*)gbr;
    uint2 pxz = *(const uint2*)gbz;
    uint2 pxn = *(const uint2*)gbn;

    __syncthreads();

    int p = 0;
    for (int t = 0; t < L_; ++t) {
        uint2 xr2 = pxr, xz2 = pxz, xn2 = pxn;
        long noff = (long)((t + 1 < L_) ? t + 1 : t) * 12288;
        pxr = *(const uint2*)(gbr + noff);
        pxz = *(const uint2*)(gbz + noff);
        pxn = *(const uint2*)(gbn + noff);

        // gates = h @ W_hh^T + b_hh   (C layout: row=quad*4+reg=batch, col=n0)
        f32x4 ar = (f32x4){bhr, bhr, bhr, bhr};
        f32x4 az = (f32x4){bhz, bhz, bhz, bhz};
        f32x4 an = (f32x4){bhn, bhn, bhn, bhn};
        const short* hp = &hB[p][0];
        #pragma unroll
        for (int tk = 0; tk < 8; ++tk) {
            short8 a = *(const short8*)&hp[c16 * 264 + tk * 32 + quad * 8];
            ar = __builtin_amdgcn_mfma_f32_16x16x32_bf16(a, wfr[tk], ar, 0, 0, 0);
            az = __builtin_amdgcn_mfma_f32_16x16x32_bf16(a, wfz[tk], az, 0, 0, 0);
            an = __builtin_amdgcn_mfma_f32_16x16x32_bf16(a, wfn[tk], an, 0, 0, 0);
        }

        float xr[4] = {bflo(xr2.x), bfhi(xr2.x), bflo(xr2.y), bfhi(xr2.y)};
        float xz[4] = {bflo(xz2.x), bfhi(xz2.x), bflo(xz2.y), bfhi(xz2.y)};
        float xn[4] = {bflo(xn2.x), bfhi(xn2.x), bflo(xn2.y), bfhi(xn2.y)};
        float hold[4] = {myh0, myh1, myh2, myh3};
        float hn[4];
        short* hw = &hB[p ^ 1][0];
        #pragma unroll
        for (int r = 0; r < 4; ++r) {
            float rr = fsigm(xr[r] + ar[r]);
            float zz = fsigm(xz[r] + az[r]);
            float cc = ftanh(xn[r] + rr * an[r]);
            hn[r] = (1.f - zz) * cc + zz * hold[r];
            hw[(quad * 4 + r) * 264 + n0] = (short)rne1(hn[r]);
        }
        myh0 = hn[0]; myh1 = hn[1]; myh2 = hn[2]; myh3 = hn[3];
        p ^= 1;
        __syncthreads();
    }

    inv_out[(long)(quad * 4 + 0) * 256 + n0] = myh0;
    inv_out[(long)(quad * 4 + 1) * 256 + n0] = myh1;
    inv_out[(long)(quad * 4 + 2) * 256 + n0] = myh2;
    inv_out[(long)(quad * 4 + 3) * 256 + n0] = myh3;
}

// ---------------------------------------------------------------------------
// scores (aa_emb bf16, aa_p f32)
// ---------------------------------------------------------------------------
__global__ void score_kernel(const float* __restrict__ aa_p, const bf16* __restrict__ aa_emb,
                             const float* __restrict__ inv, const float* __restrict__ Wab,
                             const float* __restrict__ bab, const float* __restrict__ mask,
                             float* __restrict__ out)
{
    int r = blockIdx.x * 4 + (threadIdx.x >> 6);
    int l = threadIdx.x & 63;
    int b = r / A_;
    float s = 0.f;
    for (int d = l; d < D_; d += 64)
        s += aa_p[(long)r * D_ + d] * inv[(long)b * D_ + d] +
             (float)aa_emb[(long)r * D_ + d] * Wab[d];
    #pragma unroll
    for (int off = 32; off; off >>= 1) s += __shfl_down(s, off);
    if (l == 0) {
        float lm = logf(mask[r]);
        const float MN = -3.4028234663852886e38f;
        if (!(lm >= MN)) lm = MN;
        out[r] = s + bab[0] + lm;
    }
}

// ---------------------------------------------------------------------------
// host
// ---------------------------------------------------------------------------
static inline size_t align256(size_t x) { return (x + 255) & ~(size_t)255; }

template <typename CT>
static void launch_pgemm(const bf16* A, const int* arows, const unsigned* Bp,
                         const float* bias, CT* C, int M, int K, int Nc, int relu,
                         hipStream_t s)
{
    dim3 grid(Nc / TN, (M + TM - 1) / TM);
    pgemm_kernel<CT><<<grid, 256, 0, s>>>(A, arows, Bp, bias, C, M, K, Nc, relu);
}

extern "C" void kernel_launch(void* const* d_in, const int* in_sizes, int n_in,
                              void* d_out, int out_size, void* d_ws, size_t ws_size,
                              hipStream_t stream)
{
    const int* node_tokens = (const int*)d_in[0];
    const int* edge_tokens = (const int*)d_in[1];
    const int* edge_index  = (const int*)d_in[2];
    const int* inv_token   = (const int*)d_in[3];
    const int* inv_node    = (const int*)d_in[4];
    const int* aa_token    = (const int*)d_in[5];
    const int* aa_node     = (const int*)d_in[6];
    const float* action_mask = (const float*)d_in[7];
    const float* emb   = (const float*)d_in[8];
    const float* Wq    = (const float*)d_in[9];
    const float* bq    = (const float*)d_in[10];
    const float* Wk    = (const float*)d_in[11];
    const float* bk    = (const float*)d_in[12];
    const float* Wv    = (const float*)d_in[13];
    const float* bv    = (const float*)d_in[14];
    const float* We    = (const float*)d_in[15];
    const float* Wskip = (const float*)d_in[16];
    const float* bskip = (const float*)d_in[17];
    const float* W1    = (const float*)d_in[18];
    const float* b1    = (const float*)d_in[19];
    const float* Wp    = (const float*)d_in[20];
    const float* bp    = (const float*)d_in[21];
    const float* W_ih  = (const float*)d_in[22];
    const float* W_hh  = (const float*)d_in[23];
    const float* b_ih  = (const float*)d_in[24];
    const float* b_hh  = (const float*)d_in[25];
    const float* Wab   = (const float*)d_in[26];
    const float* bab   = (const float*)d_in[27];
    const float* Wap   = (const float*)d_in[28];
    const float* bap   = (const float*)d_in[29];
    (void)in_sizes; (void)n_in; (void)out_size;

    char* base = (char*)d_ws;
    size_t off = 0;
    auto alloc = [&](size_t bytes) -> char* {
        char* p = base + off;
        off = align256(off + bytes);
        return p;
    };

    // persistent buffers
    const long VD = 50000L * 256;
    bf16*  embh       = (bf16*)alloc(VD * 2);
    float* graph_repr = (float*)alloc((size_t)B_ * N_ * D_ * 4);
    bf16*  mixed_inv  = (bf16*)alloc((size_t)B_ * L_ * D_ * 2);
    bf16*  inv_h      = (bf16*)alloc((size_t)B_ * L_ * D_ * 2);
    bf16*  gxh        = (bf16*)alloc((size_t)B_ * L_ * 768 * 2);
    bf16*  gxT        = (bf16*)alloc((size_t)B_ * L_ * 768 * 2);
    float* inv_out    = (float*)alloc((size_t)B_ * 256 * 4);
    bf16*  aa_emb     = (bf16*)alloc((size_t)B_ * A_ * D_ * 2);
    float* aa_p       = (float*)alloc((size_t)B_ * A_ * 256 * 4);
    unsigned* qkvsP   = (unsigned*)alloc((size_t)128 * 4096 * 4);
    unsigned* WeP     = (unsigned*)alloc((size_t)128 * 1024 * 4);
    unsigned* W1P     = (unsigned*)alloc((size_t)512 * 256 * 4);
    unsigned* WpP     = (unsigned*)alloc((size_t)128 * 256 * 4);
    unsigned* WihP    = (unsigned*)alloc((size_t)128 * 768 * 4);
    unsigned* WapP    = (unsigned*)alloc((size_t)128 * 256 * 4);
    short8* WhhP      = (short8*)alloc((size_t)24576 * 16);
    float* bias4096   = (float*)alloc(4096 * 4);
    size_t persist = off;

    // batch-chunk size
    int c = 16;
    while (c > 1) {
        size_t cN = (size_t)c * N_, cEs = (size_t)c * E_;
        size_t chunk = align256(cN * 4096 * 2)
                     + align256(cEs * HD_ * 2)
                     + align256(cN * HD_ * 2)
                     + align256(cEs * H_ * 4)
                     + 3 * align256(cN * 4)
                     + align256(cEs * 4);
        if (persist + chunk <= ws_size) break;
        c >>= 1;
    }
    int cN = c * N_, cE = c * E_;

    bf16*  qkvs  = (bf16*)alloc((size_t)cN * 4096 * 2);
    bf16*  ebuf  = (bf16*)alloc((size_t)cE * HD_ * 2);
    bf16*  aggb  = (bf16*)alloc((size_t)cN * HD_ * 2);
    float* ex    = (float*)alloc((size_t)cE * H_ * 4);
    int*   cnt   = (int*)alloc((size_t)cN * 4);
    int*   rstart= (int*)alloc((size_t)cN * 4);
    int*   cursor= (int*)alloc((size_t)cN * 4);
    int*   elist = (int*)alloc((size_t)cE * 4);

    // ---- pre-pass ----
    convemb_kernel<<<(int)((VD / 4 + 255) / 256), 256, 0, stream>>>(emb, embh, VD / 4);
    pack_all_kernel<<<(PACK_ALL_TOT + 255) / 256, 256, 0, stream>>>(
        Wq, Wk, Wv, Wskip, We, W1, Wp, W_ih, Wap, W_hh, bq, bk, bv, bskip,
        qkvsP, WeP, W1P, WpP, WihP, WapP, WhhP, bias4096);

    for (int b0 = 0; b0 < B_; b0 += c) {
        // CSR
        zero_int_kernel<<<(cN + 255) / 256, 256, 0, stream>>>(cnt, cN);
        count_kernel<<<(cE + 255) / 256, 256, 0, stream>>>(edge_index, b0, cnt, cE);
        scan_kernel<<<c, 1024, 0, stream>>>(cnt, rstart, cursor);
        scatter_kernel<<<(cE + 255) / 256, 256, 0, stream>>>(edge_index, b0, cursor,
                                                             elist, cE);
        // fused q|k|v|skip projection + edge projection
        launch_pgemm<bf16>(embh, node_tokens + (long)b0 * N_, qkvsP, bias4096, qkvs,
                           cN, D_, 4096, 0, stream);
        launch_pgemm<bf16>(embh, edge_tokens + (long)b0 * E_, WeP, nullptr, ebuf,
                           cE, D_, HD_, 0, stream);
        // attention
        alpha_ex_kernel<<<cE / 4, 256, 0, stream>>>(qkvs, ebuf, edge_index, b0, ex, cE);
        agg_node_kernel<<<cN, 256, 0, stream>>>(qkvs, ebuf, ex, edge_index, rstart, cnt,
                                                elist, b0, cE, aggb);
        // graph_repr = relu(aggb @ W1 + b1)
        launch_pgemm<float>(aggb, nullptr, W1P, b1,
                            graph_repr + (long)b0 * N_ * D_, cN, HD_, D_, 1, stream);
    }

    // invariant + action embeds (fused)
    mixed2_kernel<<<B_ * L_ + B_ * A_, 256, 0, stream>>>(embh, inv_token, inv_node,
                                                         aa_token, aa_node, graph_repr,
                                                         mixed_inv, aa_emb);
    launch_pgemm<bf16>(mixed_inv, nullptr, WpP, bp, inv_h, B_ * L_, D_, 256, 1, stream);
    launch_pgemm<bf16>(inv_h, nullptr, WihP, b_ih, gxh, B_ * L_, 256, 768, 0, stream);
    gxt_kernel<<<(B_ * L_ * 768 + 255) / 256, 256, 0, stream>>>(gxh, gxT);
    gru_kernel<<<1, 1024, 0, stream>>>(gxT, WhhP, b_hh, inv_out);

    // action path
    launch_pgemm<float>(aa_emb, nullptr, WapP, bap, aa_p, B_ * A_, D_, 256, 0, stream);
    score_kernel<<<(B_ * A_) / 4, 256, 0, stream>>>(aa_p, aa_emb, inv_out, Wab, bab,
                                                    action_mask, (float*)d_out);
}

// Round 10
// 880.319 us; speedup vs baseline: 1.0839x; 1.0092x over previous
//
#include <hip/hip_runtime.h>
#include <hip/hip_bf16.h>
#include <float.h>
#include <math.h>

typedef __hip_bfloat16 bf16;

#define B_ 16
#define N_ 1000
#define E_ 4000
#define L_ 64
#define A_ 128
#define D_ 256
#define H_ 4
#define HD_ 1024
#define SCALE_ 0.0625f

typedef __attribute__((ext_vector_type(8))) short short8;
typedef __attribute__((ext_vector_type(4))) float f32x4;

union U4S8 { uint4 u; short8 s; };

__device__ __forceinline__ unsigned short f2bf(float f) {
    bf16 h = __float2bfloat16(f);
    return *reinterpret_cast<unsigned short*>(&h);
}
__device__ __forceinline__ unsigned pack2(float a, float b) {
    return (unsigned)f2bf(a) | ((unsigned)f2bf(b) << 16);
}
__device__ __forceinline__ unsigned short rne1(float a) {
    unsigned ua = __float_as_uint(a);
    ua += 0x7fff + ((ua >> 16) & 1);
    return (unsigned short)(ua >> 16);
}
__device__ __forceinline__ float bflo(unsigned u) { return __uint_as_float(u << 16); }
__device__ __forceinline__ float bfhi(unsigned u) { return __uint_as_float(u & 0xffff0000u); }

#define LOG2E 1.4426950408889634f
__device__ __forceinline__ float fsigm(float x) {
    return __builtin_amdgcn_rcpf(1.f + __builtin_amdgcn_exp2f(-LOG2E * x));
}
__device__ __forceinline__ float ftanh(float x) {
    return 1.f - 2.f * __builtin_amdgcn_rcpf(1.f + __builtin_amdgcn_exp2f(2.f * LOG2E * x));
}

// ---------------------------------------------------------------------------
// Pre-pass: emb->bf16
// ---------------------------------------------------------------------------
__global__ void convemb_kernel(const float* __restrict__ src, bf16* __restrict__ dst, long n4)
{
    long i = (long)blockIdx.x * 256 + threadIdx.x;
    if (i >= n4) return;
    float4 v = *(const float4*)(src + i * 4);
    *(uint2*)(dst + i * 4) = make_uint2(pack2(v.x, v.y), pack2(v.z, v.w));
}

// ---------------------------------------------------------------------------
// Fused weight-pack pre-pass.
// WeP:  B[k=j][n]        = We[j, n]            (for xsum@We accumulation)
// WeTP: B[k=j][n=h*256+d]= We[d, h*256+j]      (for qW = We_h @ q_h)
// ---------------------------------------------------------------------------
__global__ void pack_all_kernel(const float* __restrict__ Wq, const float* __restrict__ Wk,
                                const float* __restrict__ Wv, const float* __restrict__ Wskip,
                                const float* __restrict__ We, const float* __restrict__ W1,
                                const float* __restrict__ Wp, const float* __restrict__ W_ih,
                                const float* __restrict__ Wap, const float* __restrict__ W_hh,
                                const float* __restrict__ bq, const float* __restrict__ bk,
                                const float* __restrict__ bv, const float* __restrict__ bskip,
                                unsigned* __restrict__ qkvsP, unsigned* __restrict__ WeP,
                                unsigned* __restrict__ W1P, unsigned* __restrict__ WpP,
                                unsigned* __restrict__ WihP, unsigned* __restrict__ WapP,
                                unsigned* __restrict__ WeTP,
                                short8* __restrict__ WhhP, float* __restrict__ bias4096)
{
    int i = blockIdx.x * 256 + threadIdx.x;
    if (i < 524288) {                       // qkvsP: 128 k2 x 4096
        int k2 = i >> 12, n = i & 4095;
        const float* s = (n < 1024) ? Wq : (n < 2048) ? Wk : (n < 3072) ? Wv : Wskip;
        int col = n & 1023;
        qkvsP[i] = pack2(s[(long)(2 * k2) * 1024 + col], s[(long)(2 * k2 + 1) * 1024 + col]);
        return;
    }
    i -= 524288;
    if (i < 131072) {                       // WeP: 128 x 1024
        int k2 = i >> 10, n = i & 1023;
        WeP[i] = pack2(We[(long)(2 * k2) * 1024 + n], We[(long)(2 * k2 + 1) * 1024 + n]);
        return;
    }
    i -= 131072;
    if (i < 131072) {                       // W1P: 512 k2 x 256
        int k2 = i >> 8, n = i & 255;
        W1P[i] = pack2(W1[(long)(2 * k2) * 256 + n], W1[(long)(2 * k2 + 1) * 256 + n]);
        return;
    }
    i -= 131072;
    if (i < 32768) {                        // WpP: 128 x 256
        int k2 = i >> 8, n = i & 255;
        WpP[i] = pack2(Wp[(long)(2 * k2) * 256 + n], Wp[(long)(2 * k2 + 1) * 256 + n]);
        return;
    }
    i -= 32768;
    if (i < 98304) {                        // WihP (transposed src [768,256]): 128 k2 x 768
        int k2 = i / 768, n = i % 768;
        WihP[i] = pack2(W_ih[(long)n * 256 + 2 * k2], W_ih[(long)n * 256 + 2 * k2 + 1]);
        return;
    }
    i -= 98304;
    if (i < 32768) {                        // WapP: 128 x 256
        int k2 = i >> 8, n = i & 255;
        WapP[i] = pack2(Wap[(long)(2 * k2) * 256 + n], Wap[(long)(2 * k2 + 1) * 256 + n]);
        return;
    }
    i -= 32768;
    if (i < 131072) {                       // WeTP: 128 k2 x 1024 (per-head transpose)
        int k2 = i >> 10, n = i & 1023;
        int d = n & 255, hb = n & ~255;
        WeTP[i] = pack2(We[(long)d * 1024 + hb + 2 * k2],
                        We[(long)d * 1024 + hb + 2 * k2 + 1]);
        return;
    }
    i -= 131072;
    if (i < 24576) {                        // WhhP MFMA B-frag stream (48 tiles)
        int lane = i & 63, tk = (i >> 6) & 7, tile = i >> 9;
        int n = tile * 16 + (lane & 15);
        const float* wp = W_hh + (long)n * 256 + tk * 32 + (lane >> 4) * 8;
        float4 w0 = *(const float4*)wp;
        float4 w1 = *(const float4*)(wp + 4);
        U4S8 u;
        u.u = make_uint4(pack2(w0.x, w0.y), pack2(w0.z, w0.w),
                         pack2(w1.x, w1.y), pack2(w1.z, w1.w));
        WhhP[i] = u.s;
        return;
    }
    i -= 24576;
    if (i < 4096) {                         // bias4096
        int q = i >> 10, c = i & 1023;
        bias4096[i] = ((q == 0) ? bq : (q == 1) ? bk : (q == 2) ? bv : bskip)[c];
    }
}
#define PACK_ALL_TOT (524288 + 131072 + 131072 + 32768 + 98304 + 32768 + 131072 + 24576 + 4096)

// ---------------------------------------------------------------------------
// gx transpose: gxh[B*L][768] -> gxT[t][768][16 batches]  (bf16)
// ---------------------------------------------------------------------------
__global__ void gxt_kernel(const bf16* __restrict__ gxh, bf16* __restrict__ gxT)
{
    int i = blockIdx.x * 256 + threadIdx.x;
    if (i >= B_ * L_ * 768) return;
    int b = i / (L_ * 768);
    int rem = i - b * (L_ * 768);
    int t = rem / 768, n = rem - (rem / 768) * 768;
    gxT[((long)t * 768 + n) * 16 + b] = gxh[i];
}

// ---------------------------------------------------------------------------
// MFMA GEMM: C[:, col0..] = act( A[M, K-slice] @ Bp + bias (+C) )
// astride: A row stride; aoff: A column offset (+= col0&~255 if hslice).
// ---------------------------------------------------------------------------
#define TM 128
#define TN 128
#define TK 32
#define ASTR 40
#define BSTR 132

template <typename CT>
__global__ __launch_bounds__(256)
void pgemm_kernel(const bf16* __restrict__ A, const int* __restrict__ arows,
                  const unsigned* __restrict__ Bp, const float* __restrict__ bias,
                  CT* __restrict__ C, int M, int K, int Nc, int relu_out,
                  long astride, int aoff, int colbase, int hslice, int addC)
{
    __shared__ short    As[TM * ASTR];
    __shared__ unsigned Bs[(TK / 2) * BSTR];

    const int tid  = threadIdx.x;
    const int lane = tid & 63;
    const int wave = tid >> 6;
    const int wm = wave >> 1, wn = wave & 1;
    const int quad = lane >> 4, c16 = lane & 15;
    const long row0 = (long)blockIdx.y * TM;
    const int  col0 = colbase + blockIdx.x * TN;
    const int  aoff2 = aoff + (hslice ? (col0 & ~255) : 0);

    const int sm  = tid >> 1;
    const int sh  = (tid & 1) * 16;
    const int sn2 = tid & 63;
    const int skk = (tid >> 6) * 4;

    long gr_row = row0 + sm;
    if (gr_row > M - 1) gr_row = M - 1;
    long ar = arows ? (long)arows[gr_row] : gr_row;
    const short* Arow = (const short*)A + ar * astride + aoff2 + sh;

    f32x4 acc[4][4];
    #pragma unroll
    for (int i = 0; i < 4; ++i)
        #pragma unroll
        for (int j = 0; j < 4; ++j)
            acc[i][j] = (f32x4){0.f, 0.f, 0.f, 0.f};

    for (int k0 = 0; k0 < K; k0 += TK) {
        {
            const short* p = Arow + k0;
            uint4 a = *(const uint4*)(p);
            uint4 b = *(const uint4*)(p + 8);
            *(uint4*)&As[sm * ASTR + sh]     = a;
            *(uint4*)&As[sm * ASTR + sh + 8] = b;
        }
        #pragma unroll
        for (int i = 0; i < 4; ++i) {
            int kk2 = skk + i;
            *(uint2*)&Bs[kk2 * BSTR + sn2 * 2] =
                *(const uint2*)&Bp[(long)(k0 / 2 + kk2) * Nc + col0 + sn2 * 2];
        }
        __syncthreads();

        short8 af[4];
        U4S8   bfr[4];
        #pragma unroll
        for (int mi = 0; mi < 4; ++mi) {
            int m = wm * 64 + mi * 16 + c16;
            af[mi] = *(const short8*)&As[m * ASTR + quad * 8];
        }
        #pragma unroll
        for (int ni = 0; ni < 4; ++ni) {
            int n = wn * 64 + ni * 16 + c16;
            uint4 u;
            u.x = Bs[(quad * 4 + 0) * BSTR + n];
            u.y = Bs[(quad * 4 + 1) * BSTR + n];
            u.z = Bs[(quad * 4 + 2) * BSTR + n];
            u.w = Bs[(quad * 4 + 3) * BSTR + n];
            bfr[ni].u = u;
        }
        #pragma unroll
        for (int mi = 0; mi < 4; ++mi)
            #pragma unroll
            for (int ni = 0; ni < 4; ++ni)
                acc[mi][ni] = __builtin_amdgcn_mfma_f32_16x16x32_bf16(
                    af[mi], bfr[ni].s, acc[mi][ni], 0, 0, 0);
        __syncthreads();
    }

    #pragma unroll
    for (int ni = 0; ni < 4; ++ni) {
        int col = col0 + wn * 64 + ni * 16 + c16;
        float bv = bias ? bias[col] : 0.f;
        #pragma unroll
        for (int mi = 0; mi < 4; ++mi) {
            long row = row0 + wm * 64 + mi * 16 + quad * 4;
            #pragma unroll
            for (int r = 0; r < 4; ++r) {
                if (row + r >= M) continue;
                float v = acc[mi][ni][r] + bv;
                if (addC) v += (float)C[(row + r) * Nc + col];
                if (relu_out) v = fmaxf(v, 0.f);
                C[(row + r) * Nc + col] = (CT)v;
            }
        }
    }
}

// ---------------------------------------------------------------------------
// CSR build
// ---------------------------------------------------------------------------
__global__ void zero_int_kernel(int* __restrict__ p, int n)
{
    int i = blockIdx.x * 256 + threadIdx.x;
    if (i < n) p[i] = 0;
}

__global__ void count_kernel(const int* __restrict__ edge_index, int b0,
                             int* __restrict__ cnt, int cE)
{
    int i = blockIdx.x * 256 + threadIdx.x;
    if (i >= cE) return;
    int bl = i / E_, ei = i % E_;
    int dst = edge_index[(long)(b0 + bl) * 2 * E_ + E_ + ei];
    atomicAdd(&cnt[bl * N_ + dst], 1);
}

__global__ __launch_bounds__(1024)
void scan_kernel(const int* __restrict__ cnt, int* __restrict__ row_start,
                 int* __restrict__ cursor)
{
    int bl = blockIdx.x;
    int tid = threadIdx.x;
    __shared__ int s[1024];
    int v = (tid < N_) ? cnt[bl * N_ + tid] : 0;
    s[tid] = v;
    __syncthreads();
    for (int off = 1; off < 1024; off <<= 1) {
        int t = (tid >= off) ? s[tid - off] : 0;
        __syncthreads();
        s[tid] += t;
        __syncthreads();
    }
    if (tid < N_) {
        int excl = s[tid] - v;
        row_start[bl * N_ + tid] = excl;
        cursor[bl * N_ + tid] = excl;
    }
}

__global__ void scatter_kernel(const int* __restrict__ edge_index, int b0,
                               int* __restrict__ cursor, int* __restrict__ elist, int cE)
{
    int i = blockIdx.x * 256 + threadIdx.x;
    if (i >= cE) return;
    int bl = i / E_, ei = i % E_;
    int dst = edge_index[(long)(b0 + bl) * 2 * E_ + E_ + ei];
    int pos = atomicAdd(&cursor[bl * N_ + dst], 1);
    elist[bl * E_ + pos] = ei;
}

// ---------------------------------------------------------------------------
// alpha_ex: s = q[dst]·k[src] + qW[dst]·x_edge ;  ex = exp2(s*SCALE*log2e)
// e never materialized: q·e == (We_h q_h)·x  (qW precomputed node-side).
// ---------------------------------------------------------------------------
__device__ __forceinline__ float d2(unsigned a, unsigned b)
{
    return bflo(a) * bflo(b) + bfhi(a) * bfhi(b);
}

__global__ void alpha_ex_kernel(const bf16* __restrict__ qkvs, const bf16* __restrict__ qWb,
                                const bf16* __restrict__ embh, const int* __restrict__ edge_tokens,
                                const int* __restrict__ edge_index,
                                int b0, float* __restrict__ ex, int cE)
{
    int eidx = blockIdx.x * 4 + (threadIdx.x >> 6);
    int l = threadIdx.x & 63;
    int bl = eidx / E_, ei = eidx % E_;
    const int* eb = edge_index + (long)(b0 + bl) * 2 * E_;
    int src = eb[ei], dst = eb[E_ + ei];
    int tok = edge_tokens[(long)(b0 + bl) * E_ + ei];
    int head = l >> 4;
    int li = l & 15;
    int joff = head * 256 + li * 16;

    const uint4* qp = (const uint4*)(qkvs + (long)(bl * N_ + dst) * 4096 + joff);
    const uint4* kp = (const uint4*)(qkvs + (long)(bl * N_ + src) * 4096 + 1024 + joff);
    const uint4* wp = (const uint4*)(qWb + (long)(bl * N_ + dst) * 1024 + joff);
    const uint4* xp = (const uint4*)(embh + (long)tok * 256 + li * 16);

    uint4 qa = qp[0], qb2 = qp[1];
    uint4 ka = kp[0], kb2 = kp[1];
    uint4 wa = wp[0], wb2 = wp[1];
    uint4 xa = xp[0], xb2 = xp[1];

    float s = d2(qa.x, ka.x) + d2(qa.y, ka.y) + d2(qa.z, ka.z) + d2(qa.w, ka.w)
            + d2(qb2.x, kb2.x) + d2(qb2.y, kb2.y) + d2(qb2.z, kb2.z) + d2(qb2.w, kb2.w)
            + d2(wa.x, xa.x) + d2(wa.y, xa.y) + d2(wa.z, xa.z) + d2(wa.w, xa.w)
            + d2(wb2.x, xb2.x) + d2(wb2.y, xb2.y) + d2(wb2.z, xb2.z) + d2(wb2.w, xb2.w);

    s += __shfl_down(s, 8);
    s += __shfl_down(s, 4);
    s += __shfl_down(s, 2);
    s += __shfl_down(s, 1);

    if (li == 0)
        ex[(long)head * cE + eidx] = __builtin_amdgcn_exp2f(s * (SCALE_ * LOG2E));
}

// ---------------------------------------------------------------------------
// agg_node: per node, CSR reduce:
//   aggb  = Σ w·v[src] + skip          (bf16, NO relu — e-GEMM adds & relus)
//   xsumb = Σ w_h·x_edge  (per head)   (bf16, [n, h*256+j] == [n, tid*4])
// ---------------------------------------------------------------------------
__global__ void agg_node_kernel(const bf16* __restrict__ qkvs, const bf16* __restrict__ embh,
                                const int* __restrict__ edge_tokens,
                                const float* __restrict__ ex, const int* __restrict__ edge_index,
                                const int* __restrict__ row_start, const int* __restrict__ cnt,
                                const int* __restrict__ elist,
                                int b0, int cE, bf16* __restrict__ aggb,
                                bf16* __restrict__ xsumb)
{
    int base = blockIdx.x;
    int bl = base / N_;
    int tid = threadIdx.x;
    int h = tid >> 6;
    int j0 = tid * 4;            // v/skip col (1024-wide), also xsum flat col
    int jx = (tid & 63) * 4;     // x col (256-wide)

    int start = row_start[base];
    int deg = cnt[base];
    const int* el = elist + (long)bl * E_;
    const float* exh = ex + (long)h * cE;
    const int* srcp = edge_index + (long)(b0 + bl) * 2 * E_;
    const int* tokp = edge_tokens + (long)(b0 + bl) * E_;

    float d = 0.f;
    for (int t = 0; t < deg; ++t)
        d += exh[(long)bl * E_ + el[start + t]];
    float invd = (deg > 0) ? 1.f / d : 0.f;

    float a0 = 0.f, a1 = 0.f, a2 = 0.f, a3 = 0.f;
    float x0 = 0.f, x1 = 0.f, x2 = 0.f, x3 = 0.f;
    for (int t = 0; t < deg; ++t) {
        int ei = el[start + t];
        long eidx = (long)bl * E_ + ei;
        float w = exh[eidx] * invd;
        int src = srcp[ei];
        int tok = tokp[ei];
        uint2 vv = *(const uint2*)(qkvs + (long)(bl * N_ + src) * 4096 + 2048 + j0);
        uint2 xx = *(const uint2*)(embh + (long)tok * 256 + jx);
        a0 += w * bflo(vv.x);
        a1 += w * bfhi(vv.x);
        a2 += w * bflo(vv.y);
        a3 += w * bfhi(vv.y);
        x0 += w * bflo(xx.x);
        x1 += w * bfhi(xx.x);
        x2 += w * bflo(xx.y);
        x3 += w * bfhi(xx.y);
    }

    uint2 sk = *(const uint2*)(qkvs + (long)base * 4096 + 3072 + j0);
    unsigned o0 = pack2(bflo(sk.x) + a0, bfhi(sk.x) + a1);
    unsigned o1 = pack2(bflo(sk.y) + a2, bfhi(sk.y) + a3);
    *(uint2*)(aggb + (long)base * HD_ + j0) = make_uint2(o0, o1);
    *(uint2*)(xsumb + (long)base * HD_ + j0) = make_uint2(pack2(x0, x1), pack2(x2, x3));
}

// ---------------------------------------------------------------------------
// fused mixed embed (inv rows then aa rows) -> bf16
// ---------------------------------------------------------------------------
__global__ void mixed2_kernel(const bf16* __restrict__ embh,
                              const int* __restrict__ inv_token, const int* __restrict__ inv_node,
                              const int* __restrict__ aa_token, const int* __restrict__ aa_node,
                              const float* __restrict__ graph_repr,
                              bf16* __restrict__ mixed_inv, bf16* __restrict__ aa_emb)
{
    int r = blockIdx.x;
    int d = threadIdx.x;
    if (r < B_ * L_) {
        int b = r / L_;
        float v = (float)embh[(long)inv_token[r] * D_ + d] +
                  graph_repr[((long)b * N_ + inv_node[r]) * D_ + d];
        mixed_inv[(long)r * D_ + d] = __float2bfloat16(v);
    } else {
        int r2 = r - B_ * L_;
        int b = r2 / A_;
        float v = (float)embh[(long)aa_token[r2] * D_ + d] +
                  graph_repr[((long)b * N_ + aa_node[r2]) * D_ + d];
        aa_emb[(long)r2 * D_ + d] = __float2bfloat16(v);
    }
}

// ---------------------------------------------------------------------------
// GRU via MFMA, gates in-register (round-9 structure, kept)
// ---------------------------------------------------------------------------
__global__ __launch_bounds__(1024)
void gru_kernel(const bf16* __restrict__ gxT, const short8* __restrict__ WhhP,
                const float* __restrict__ b_hh, float* __restrict__ inv_out)
{
    __shared__ short hB[2][16 * 264];

    const int tid = threadIdx.x;
    const int lane = tid & 63;
    const int wave = tid >> 6;
    const int quad = lane >> 4, c16 = lane & 15;
    const int n0 = wave * 16 + c16;

    for (int i = tid; i < 2 * 16 * 264; i += 1024) ((short*)hB)[i] = 0;

    short8 wfr[8], wfz[8], wfn[8];
    #pragma unroll
    for (int tk = 0; tk < 8; ++tk) {
        wfr[tk] = WhhP[((0 * 16 + wave) * 8 + tk) * 64 + lane];
        wfz[tk] = WhhP[((1 * 16 + wave) * 8 + tk) * 64 + lane];
        wfn[tk] = WhhP[((2 * 16 + wave) * 8 + tk) * 64 + lane];
    }
    float bhr = b_hh[0 * 256 + n0];
    float bhz = b_hh[1 * 256 + n0];
    float bhn = b_hh[2 * 256 + n0];

    float myh0 = 0.f, myh1 = 0.f, myh2 = 0.f, myh3 = 0.f;

    const short* gbr = (const short*)gxT + (long)(0 * 256 + n0) * 16 + quad * 4;
    const short* gbz = gbr + 256 * 16;
    const short* gbn = gbr + 512 * 16;

    uint2 pxr = *(const uint2*)gbr;
    uint2 pxz = *(const uint2*)gbz;
    uint2 pxn = *(const uint2*)gbn;

    __syncthreads();

    int p = 0;
    for (int t = 0; t < L_; ++t) {
        uint2 xr2 = pxr, xz2 = pxz, xn2 = pxn;
        long noff = (long)((t + 1 < L_) ? t + 1 : t) * 12288;
        pxr = *(const uint2*)(gbr + noff);
        pxz = *(const uint2*)(gbz + noff);
        pxn = *(const uint2*)(gbn + noff);

        f32x4 ar = (f32x4){bhr, bhr, bhr, bhr};
        f32x4 az = (f32x4){bhz, bhz, bhz, bhz};
        f32x4 an = (f32x4){bhn, bhn, bhn, bhn};
        const short* hp = &hB[p][0];
        #pragma unroll
        for (int tk = 0; tk < 8; ++tk) {
            short8 a = *(const short8*)&hp[c16 * 264 + tk * 32 + quad * 8];
            ar = __builtin_amdgcn_mfma_f32_16x16x32_bf16(a, wfr[tk], ar, 0, 0, 0);
            az = __builtin_amdgcn_mfma_f32_16x16x32_bf16(a, wfz[tk], az, 0, 0, 0);
            an = __builtin_amdgcn_mfma_f32_16x16x32_bf16(a, wfn[tk], an, 0, 0, 0);
        }

        float xr[4] = {bflo(xr2.x), bfhi(xr2.x), bflo(xr2.y), bfhi(xr2.y)};
        float xz[4] = {bflo(xz2.x), bfhi(xz2.x), bflo(xz2.y), bfhi(xz2.y)};
        float xn[4] = {bflo(xn2.x), bfhi(xn2.x), bflo(xn2.y), bfhi(xn2.y)};
        float hold[4] = {myh0, myh1, myh2, myh3};
        float hn[4];
        short* hw = &hB[p ^ 1][0];
        #pragma unroll
        for (int r = 0; r < 4; ++r) {
            float rr = fsigm(xr[r] + ar[r]);
            float zz = fsigm(xz[r] + az[r]);
            float cc = ftanh(xn[r] + rr * an[r]);
            hn[r] = (1.f - zz) * cc + zz * hold[r];
            hw[(quad * 4 + r) * 264 + n0] = (short)rne1(hn[r]);
        }
        myh0 = hn[0]; myh1 = hn[1]; myh2 = hn[2]; myh3 = hn[3];
        p ^= 1;
        __syncthreads();
    }

    inv_out[(long)(quad * 4 + 0) * 256 + n0] = myh0;
    inv_out[(long)(quad * 4 + 1) * 256 + n0] = myh1;
    inv_out[(long)(quad * 4 + 2) * 256 + n0] = myh2;
    inv_out[(long)(quad * 4 + 3) * 256 + n0] = myh3;
}

// ---------------------------------------------------------------------------
// scores
// ---------------------------------------------------------------------------
__global__ void score_kernel(const float* __restrict__ aa_p, const bf16* __restrict__ aa_emb,
                             const float* __restrict__ inv, const float* __restrict__ Wab,
                             const float* __restrict__ bab, const float* __restrict__ mask,
                             float* __restrict__ out)
{
    int r = blockIdx.x * 4 + (threadIdx.x >> 6);
    int l = threadIdx.x & 63;
    int b = r / A_;
    float s = 0.f;
    for (int d = l; d < D_; d += 64)
        s += aa_p[(long)r * D_ + d] * inv[(long)b * D_ + d] +
             (float)aa_emb[(long)r * D_ + d] * Wab[d];
    #pragma unroll
    for (int off = 32; off; off >>= 1) s += __shfl_down(s, off);
    if (l == 0) {
        float lm = logf(mask[r]);
        const float MN = -3.4028234663852886e38f;
        if (!(lm >= MN)) lm = MN;
        out[r] = s + bab[0] + lm;
    }
}

// ---------------------------------------------------------------------------
// host
// ---------------------------------------------------------------------------
static inline size_t align256(size_t x) { return (x + 255) & ~(size_t)255; }

template <typename CT>
static void launch_pgemm(const bf16* A, const int* arows, const unsigned* Bp,
                         const float* bias, CT* C, int M, int K, int Nc, int relu,
                         long astride, int aoff, int colbase, int hslice, int addC,
                         int ncols, hipStream_t s)
{
    dim3 grid(ncols / TN, (M + TM - 1) / TM);
    pgemm_kernel<CT><<<grid, 256, 0, s>>>(A, arows, Bp, bias, C, M, K, Nc, relu,
                                          astride, aoff, colbase, hslice, addC);
}

extern "C" void kernel_launch(void* const* d_in, const int* in_sizes, int n_in,
                              void* d_out, int out_size, void* d_ws, size_t ws_size,
                              hipStream_t stream)
{
    const int* node_tokens = (const int*)d_in[0];
    const int* edge_tokens = (const int*)d_in[1];
    const int* edge_index  = (const int*)d_in[2];
    const int* inv_token   = (const int*)d_in[3];
    const int* inv_node    = (const int*)d_in[4];
    const int* aa_token    = (const int*)d_in[5];
    const int* aa_node     = (const int*)d_in[6];
    const float* action_mask = (const float*)d_in[7];
    const float* emb   = (const float*)d_in[8];
    const float* Wq    = (const float*)d_in[9];
    const float* bq    = (const float*)d_in[10];
    const float* Wk    = (const float*)d_in[11];
    const float* bk    = (const float*)d_in[12];
    const float* Wv    = (const float*)d_in[13];
    const float* bv    = (const float*)d_in[14];
    const float* We    = (const float*)d_in[15];
    const float* Wskip = (const float*)d_in[16];
    const float* bskip = (const float*)d_in[17];
    const float* W1    = (const float*)d_in[18];
    const float* b1    = (const float*)d_in[19];
    const float* Wp    = (const float*)d_in[20];
    const float* bp    = (const float*)d_in[21];
    const float* W_ih  = (const float*)d_in[22];
    const float* W_hh  = (const float*)d_in[23];
    const float* b_ih  = (const float*)d_in[24];
    const float* b_hh  = (const float*)d_in[25];
    const float* Wab   = (const float*)d_in[26];
    const float* bab   = (const float*)d_in[27];
    const float* Wap   = (const float*)d_in[28];
    const float* bap   = (const float*)d_in[29];
    (void)in_sizes; (void)n_in; (void)out_size;

    char* base = (char*)d_ws;
    size_t off = 0;
    auto alloc = [&](size_t bytes) -> char* {
        char* p = base + off;
        off = align256(off + bytes);
        return p;
    };

    // persistent buffers
    const long VD = 50000L * 256;
    bf16*  embh       = (bf16*)alloc(VD * 2);
    float* graph_repr = (float*)alloc((size_t)B_ * N_ * D_ * 4);
    bf16*  mixed_inv  = (bf16*)alloc((size_t)B_ * L_ * D_ * 2);
    bf16*  inv_h      = (bf16*)alloc((size_t)B_ * L_ * D_ * 2);
    bf16*  gxh        = (bf16*)alloc((size_t)B_ * L_ * 768 * 2);
    bf16*  gxT        = (bf16*)alloc((size_t)B_ * L_ * 768 * 2);
    float* inv_out    = (float*)alloc((size_t)B_ * 256 * 4);
    bf16*  aa_emb     = (bf16*)alloc((size_t)B_ * A_ * D_ * 2);
    float* aa_p       = (float*)alloc((size_t)B_ * A_ * 256 * 4);
    unsigned* qkvsP   = (unsigned*)alloc((size_t)128 * 4096 * 4);
    unsigned* WeP     = (unsigned*)alloc((size_t)128 * 1024 * 4);
    unsigned* W1P     = (unsigned*)alloc((size_t)512 * 256 * 4);
    unsigned* WpP     = (unsigned*)alloc((size_t)128 * 256 * 4);
    unsigned* WihP    = (unsigned*)alloc((size_t)128 * 768 * 4);
    unsigned* WapP    = (unsigned*)alloc((size_t)128 * 256 * 4);
    unsigned* WeTP    = (unsigned*)alloc((size_t)128 * 1024 * 4);
    short8* WhhP      = (short8*)alloc((size_t)24576 * 16);
    float* bias4096   = (float*)alloc(4096 * 4);
    size_t persist = off;

    // batch-chunk size
    int c = 16;
    while (c > 1) {
        size_t cN = (size_t)c * N_, cEs = (size_t)c * E_;
        size_t chunk = align256(cN * 4096 * 2)       // qkvs
                     + align256(cN * HD_ * 2)        // qWb
                     + align256(cN * HD_ * 2)        // aggb
                     + align256(cN * HD_ * 2)        // xsumb
                     + align256(cEs * H_ * 4)        // ex
                     + 3 * align256(cN * 4)
                     + align256(cEs * 4);
        if (persist + chunk <= ws_size) break;
        c >>= 1;
    }
    int cN = c * N_, cE = c * E_;

    bf16*  qkvs  = (bf16*)alloc((size_t)cN * 4096 * 2);
    bf16*  qWb   = (bf16*)alloc((size_t)cN * HD_ * 2);
    bf16*  aggb  = (bf16*)alloc((size_t)cN * HD_ * 2);
    bf16*  xsumb = (bf16*)alloc((size_t)cN * HD_ * 2);
    float* ex    = (float*)alloc((size_t)cE * H_ * 4);
    int*   cnt   = (int*)alloc((size_t)cN * 4);
    int*   rstart= (int*)alloc((size_t)cN * 4);
    int*   cursor= (int*)alloc((size_t)cN * 4);
    int*   elist = (int*)alloc((size_t)cE * 4);

    // ---- pre-pass ----
    convemb_kernel<<<(int)((VD / 4 + 255) / 256), 256, 0, stream>>>(emb, embh, VD / 4);
    pack_all_kernel<<<(PACK_ALL_TOT + 255) / 256, 256, 0, stream>>>(
        Wq, Wk, Wv, Wskip, We, W1, Wp, W_ih, Wap, W_hh, bq, bk, bv, bskip,
        qkvsP, WeP, W1P, WpP, WihP, WapP, WeTP, WhhP, bias4096);

    for (int b0 = 0; b0 < B_; b0 += c) {
        // CSR
        zero_int_kernel<<<(cN + 255) / 256, 256, 0, stream>>>(cnt, cN);
        count_kernel<<<(cE + 255) / 256, 256, 0, stream>>>(edge_index, b0, cnt, cE);
        scan_kernel<<<c, 1024, 0, stream>>>(cnt, rstart, cursor);
        scatter_kernel<<<(cE + 255) / 256, 256, 0, stream>>>(edge_index, b0, cursor,
                                                             elist, cE);
        // fused q|k|v|skip projection (gathered from embh)
        launch_pgemm<bf16>(embh, node_tokens + (long)b0 * N_, qkvsP, bias4096, qkvs,
                           cN, D_, 4096, 0, 256, 0, 0, 0, 0, 4096, stream);
        // qW[n, h*256+d] = We_h @ q_h  (per-head K-slice of qkvs)
        launch_pgemm<bf16>(qkvs, nullptr, WeTP, nullptr, qWb,
                           cN, 256, 1024, 0, 4096, 0, 0, 1, 0, 1024, stream);
        // attention (e never materialized)
        alpha_ex_kernel<<<cE / 4, 256, 0, stream>>>(qkvs, qWb, embh, edge_tokens,
                                                    edge_index, b0, ex, cE);
        agg_node_kernel<<<cN, 256, 0, stream>>>(qkvs, embh, edge_tokens, ex, edge_index,
                                                rstart, cnt, elist, b0, cE, aggb, xsumb);
        // aggb += xsum_h @ We_h ; relu   (per-head K-slice, accumulate)
        launch_pgemm<bf16>(xsumb, nullptr, WeP, nullptr, aggb,
                           cN, 256, 1024, 1, 1024, 0, 0, 1, 1, 1024, stream);
        // graph_repr = relu(aggb @ W1 + b1)
        launch_pgemm<float>(aggb, nullptr, W1P, b1,
                            graph_repr + (long)b0 * N_ * D_,
                            cN, HD_, D_, 1, 1024, 0, 0, 0, 0, 256, stream);
    }

    // invariant + action embeds (fused)
    mixed2_kernel<<<B_ * L_ + B_ * A_, 256, 0, stream>>>(embh, inv_token, inv_node,
                                                         aa_token, aa_node, graph_repr,
                                                         mixed_inv, aa_emb);
    launch_pgemm<bf16>(mixed_inv, nullptr, WpP, bp, inv_h,
                       B_ * L_, D_, 256, 1, 256, 0, 0, 0, 0, 256, stream);
    launch_pgemm<bf16>(inv_h, nullptr, WihP, b_ih, gxh,
                       B_ * L_, 256, 768, 0, 256, 0, 0, 0, 0, 768, stream);
    gxt_kernel<<<(B_ * L_ * 768 + 255) / 256, 256, 0, stream>>>(gxh, gxT);
    gru_kernel<<<1, 1024, 0, stream>>>(gxT, WhhP, b_hh, inv_out);

    // action path
    launch_pgemm<float>(aa_emb, nullptr, WapP, bap, aa_p,
                        B_ * A_, D_, 256, 0, 256, 0, 0, 0, 0, 256, stream);
    score_kernel<<<(B_ * A_) / 4, 256, 0, stream>>>(aa_p, aa_emb, inv_out, Wab, bab,
                                                    action_mask, (float*)d_out);
}

// Round 11
// 849.209 us; speedup vs baseline: 1.1236x; 1.0366x over previous
//
#include <hip/hip_runtime.h>
#include <hip/hip_bf16.h>
#include <float.h>
#include <math.h>

typedef __hip_bfloat16 bf16;

#define B_ 16
#define N_ 1000
#define E_ 4000
#define L_ 64
#define A_ 128
#define D_ 256
#define H_ 4
#define HD_ 1024
#define SCALE_ 0.0625f

typedef __attribute__((ext_vector_type(8))) short short8;
typedef __attribute__((ext_vector_type(4))) float f32x4;

union U4S8 { uint4 u; short8 s; };

__device__ __forceinline__ unsigned short f2bf(float f) {
    bf16 h = __float2bfloat16(f);
    return *reinterpret_cast<unsigned short*>(&h);
}
__device__ __forceinline__ unsigned pack2(float a, float b) {
    return (unsigned)f2bf(a) | ((unsigned)f2bf(b) << 16);
}
__device__ __forceinline__ unsigned short rne1(float a) {
    unsigned ua = __float_as_uint(a);
    ua += 0x7fff + ((ua >> 16) & 1);
    return (unsigned short)(ua >> 16);
}
__device__ __forceinline__ float bflo(unsigned u) { return __uint_as_float(u << 16); }
__device__ __forceinline__ float bfhi(unsigned u) { return __uint_as_float(u & 0xffff0000u); }

#define LOG2E 1.4426950408889634f
__device__ __forceinline__ float fsigm(float x) {
    return __builtin_amdgcn_rcpf(1.f + __builtin_amdgcn_exp2f(-LOG2E * x));
}
__device__ __forceinline__ float ftanh(float x) {
    return 1.f - 2.f * __builtin_amdgcn_rcpf(1.f + __builtin_amdgcn_exp2f(2.f * LOG2E * x));
}

// async global->LDS, 16B per lane; LDS dest = wave-uniform base + lane*16
typedef const __attribute__((address_space(1))) unsigned int* gas_t;
typedef __attribute__((address_space(3))) unsigned int* las_t;
__device__ __forceinline__ void gld16(const void* g, void* l) {
    __builtin_amdgcn_global_load_lds((gas_t)g, (las_t)l, 16, 0, 0);
}

// ---------------------------------------------------------------------------
// Pre-pass: emb->bf16
// ---------------------------------------------------------------------------
__global__ void convemb_kernel(const float* __restrict__ src, bf16* __restrict__ dst, long n4)
{
    long i = (long)blockIdx.x * 256 + threadIdx.x;
    if (i >= n4) return;
    float4 v = *(const float4*)(src + i * 4);
    *(uint2*)(dst + i * 4) = make_uint2(pack2(v.x, v.y), pack2(v.z, v.w));
}

// ---------------------------------------------------------------------------
// Fused weight-pack pre-pass
// ---------------------------------------------------------------------------
__global__ void pack_all_kernel(const float* __restrict__ Wq, const float* __restrict__ Wk,
                                const float* __restrict__ Wv, const float* __restrict__ Wskip,
                                const float* __restrict__ We, const float* __restrict__ W1,
                                const float* __restrict__ Wp, const float* __restrict__ W_ih,
                                const float* __restrict__ Wap, const float* __restrict__ W_hh,
                                const float* __restrict__ bq, const float* __restrict__ bk,
                                const float* __restrict__ bv, const float* __restrict__ bskip,
                                unsigned* __restrict__ qkvsP, unsigned* __restrict__ WeP,
                                unsigned* __restrict__ W1P, unsigned* __restrict__ WpP,
                                unsigned* __restrict__ WihP, unsigned* __restrict__ WapP,
                                unsigned* __restrict__ WeTP,
                                short8* __restrict__ WhhP, float* __restrict__ bias4096)
{
    int i = blockIdx.x * 256 + threadIdx.x;
    if (i < 524288) {                       // qkvsP: 128 k2 x 4096
        int k2 = i >> 12, n = i & 4095;
        const float* s = (n < 1024) ? Wq : (n < 2048) ? Wk : (n < 3072) ? Wv : Wskip;
        int col = n & 1023;
        qkvsP[i] = pack2(s[(long)(2 * k2) * 1024 + col], s[(long)(2 * k2 + 1) * 1024 + col]);
        return;
    }
    i -= 524288;
    if (i < 131072) {                       // WeP: 128 x 1024
        int k2 = i >> 10, n = i & 1023;
        WeP[i] = pack2(We[(long)(2 * k2) * 1024 + n], We[(long)(2 * k2 + 1) * 1024 + n]);
        return;
    }
    i -= 131072;
    if (i < 131072) {                       // W1P: 512 k2 x 256
        int k2 = i >> 8, n = i & 255;
        W1P[i] = pack2(W1[(long)(2 * k2) * 256 + n], W1[(long)(2 * k2 + 1) * 256 + n]);
        return;
    }
    i -= 131072;
    if (i < 32768) {                        // WpP: 128 x 256
        int k2 = i >> 8, n = i & 255;
        WpP[i] = pack2(Wp[(long)(2 * k2) * 256 + n], Wp[(long)(2 * k2 + 1) * 256 + n]);
        return;
    }
    i -= 32768;
    if (i < 98304) {                        // WihP (transposed src [768,256]): 128 k2 x 768
        int k2 = i / 768, n = i % 768;
        WihP[i] = pack2(W_ih[(long)n * 256 + 2 * k2], W_ih[(long)n * 256 + 2 * k2 + 1]);
        return;
    }
    i -= 98304;
    if (i < 32768) {                        // WapP: 128 x 256
        int k2 = i >> 8, n = i & 255;
        WapP[i] = pack2(Wap[(long)(2 * k2) * 256 + n], Wap[(long)(2 * k2 + 1) * 256 + n]);
        return;
    }
    i -= 32768;
    if (i < 131072) {                       // WeTP: 128 k2 x 1024 (per-head transpose)
        int k2 = i >> 10, n = i & 1023;
        int d = n & 255, hb = n & ~255;
        WeTP[i] = pack2(We[(long)d * 1024 + hb + 2 * k2],
                        We[(long)d * 1024 + hb + 2 * k2 + 1]);
        return;
    }
    i -= 131072;
    if (i < 24576) {                        // WhhP MFMA B-frag stream (48 tiles)
        int lane = i & 63, tk = (i >> 6) & 7, tile = i >> 9;
        int n = tile * 16 + (lane & 15);
        const float* wp = W_hh + (long)n * 256 + tk * 32 + (lane >> 4) * 8;
        float4 w0 = *(const float4*)wp;
        float4 w1 = *(const float4*)(wp + 4);
        U4S8 u;
        u.u = make_uint4(pack2(w0.x, w0.y), pack2(w0.z, w0.w),
                         pack2(w1.x, w1.y), pack2(w1.z, w1.w));
        WhhP[i] = u.s;
        return;
    }
    i -= 24576;
    if (i < 4096) {                         // bias4096
        int q = i >> 10, c = i & 1023;
        bias4096[i] = ((q == 0) ? bq : (q == 1) ? bk : (q == 2) ? bv : bskip)[c];
    }
}
#define PACK_ALL_TOT (524288 + 131072 + 131072 + 32768 + 98304 + 32768 + 131072 + 24576 + 4096)

// ---------------------------------------------------------------------------
// MFMA GEMM v2: A staged via global_load_lds (async, unpadded LDS tile),
// B manual padded.  C[:, col0..] = act( A[M,K-slice] @ Bp + bias (+C) ).
// outT: write bf16 C to gxT layout [t][Nc][16] with row = b*64+t.
// ---------------------------------------------------------------------------
#define TM 128
#define TN 128
#define TK 32
#define BSTR 132

template <typename CT>
__global__ __launch_bounds__(256)
void pgemm_kernel(const bf16* __restrict__ A, const int* __restrict__ arows,
                  const unsigned* __restrict__ Bp, const float* __restrict__ bias,
                  CT* __restrict__ C, int M, int K, int Nc, int relu_out,
                  long astride, int aoff, int colbase, int hslice, int addC, int outT)
{
    __shared__ short    As[TM * TK];          // unpadded: row r at shorts [r*32, r*32+32)
    __shared__ unsigned Bs[(TK / 2) * BSTR];

    const int tid  = threadIdx.x;
    const int lane = tid & 63;
    const int wave = tid >> 6;
    const int wm = wave >> 1, wn = wave & 1;
    const int quad = lane >> 4, c16 = lane & 15;
    const long row0 = (long)blockIdx.y * TM;
    const int  col0 = colbase + blockIdx.x * TN;
    const int  aoff2 = aoff + (hslice ? (col0 & ~255) : 0);

    // A staging: wave covers rows [wave*32, wave*32+32); two gld16 per lane.
    {
    }
    const int r0 = wave * 32 + (lane >> 2);
    const int cseg = (lane & 3) * 8;          // shorts
    long gr0 = row0 + r0;      if (gr0 > M - 1) gr0 = M - 1;
    long gr1 = row0 + r0 + 16; if (gr1 > M - 1) gr1 = M - 1;
    long ar0 = arows ? (long)arows[gr0] : gr0;
    long ar1 = arows ? (long)arows[gr1] : gr1;
    const short* Ag0 = (const short*)A + ar0 * astride + aoff2 + cseg;
    const short* Ag1 = (const short*)A + ar1 * astride + aoff2 + cseg;
    short* Ld0 = &As[wave * 1024];            // call 0: rows wave*32..+15
    short* Ld1 = &As[wave * 1024 + 512];      // call 1: rows wave*32+16..+31

    // B staging indices
    const int sn2 = tid & 63;
    const int skk = wave * 4;

    f32x4 acc[4][4];
    #pragma unroll
    for (int i = 0; i < 4; ++i)
        #pragma unroll
        for (int j = 0; j < 4; ++j)
            acc[i][j] = (f32x4){0.f, 0.f, 0.f, 0.f};

    for (int k0 = 0; k0 < K; k0 += TK) {
        gld16(Ag0 + k0, Ld0);
        gld16(Ag1 + k0, Ld1);
        #pragma unroll
        for (int i = 0; i < 4; ++i) {
            int kk2 = skk + i;
            *(uint2*)&Bs[kk2 * BSTR + sn2 * 2] =
                *(const uint2*)&Bp[(long)(k0 / 2 + kk2) * Nc + col0 + sn2 * 2];
        }
        __syncthreads();

        short8 af[4];
        U4S8   bfr[4];
        #pragma unroll
        for (int mi = 0; mi < 4; ++mi) {
            int m = wm * 64 + mi * 16 + c16;
            af[mi] = *(const short8*)&As[m * 32 + quad * 8];
        }
        #pragma unroll
        for (int ni = 0; ni < 4; ++ni) {
            int n = wn * 64 + ni * 16 + c16;
            uint4 u;
            u.x = Bs[(quad * 4 + 0) * BSTR + n];
            u.y = Bs[(quad * 4 + 1) * BSTR + n];
            u.z = Bs[(quad * 4 + 2) * BSTR + n];
            u.w = Bs[(quad * 4 + 3) * BSTR + n];
            bfr[ni].u = u;
        }
        #pragma unroll
        for (int mi = 0; mi < 4; ++mi)
            #pragma unroll
            for (int ni = 0; ni < 4; ++ni)
                acc[mi][ni] = __builtin_amdgcn_mfma_f32_16x16x32_bf16(
                    af[mi], bfr[ni].s, acc[mi][ni], 0, 0, 0);
        __syncthreads();
    }

    #pragma unroll
    for (int ni = 0; ni < 4; ++ni) {
        int col = col0 + wn * 64 + ni * 16 + c16;
        float bv = bias ? bias[col] : 0.f;
        #pragma unroll
        for (int mi = 0; mi < 4; ++mi) {
            long row = row0 + wm * 64 + mi * 16 + quad * 4;
            #pragma unroll
            for (int r = 0; r < 4; ++r) {
                if (row + r >= M) continue;
                float v = acc[mi][ni][r] + bv;
                if (addC) v += (float)C[(row + r) * Nc + col];
                if (relu_out) v = fmaxf(v, 0.f);
                if (outT) {
                    long rr = row + r;
                    int t = (int)(rr & 63), b = (int)(rr >> 6);
                    C[((long)t * Nc + col) * 16 + b] = (CT)v;
                } else {
                    C[(row + r) * Nc + col] = (CT)v;
                }
            }
        }
    }
}

// ---------------------------------------------------------------------------
// CSR build
// ---------------------------------------------------------------------------
__global__ void zero_int_kernel(int* __restrict__ p, int n)
{
    int i = blockIdx.x * 256 + threadIdx.x;
    if (i < n) p[i] = 0;
}

__global__ void count_kernel(const int* __restrict__ edge_index, int b0,
                             int* __restrict__ cnt, int cE)
{
    int i = blockIdx.x * 256 + threadIdx.x;
    if (i >= cE) return;
    int bl = i / E_, ei = i % E_;
    int dst = edge_index[(long)(b0 + bl) * 2 * E_ + E_ + ei];
    atomicAdd(&cnt[bl * N_ + dst], 1);
}

__global__ __launch_bounds__(1024)
void scan_kernel(const int* __restrict__ cnt, int* __restrict__ row_start,
                 int* __restrict__ cursor)
{
    int bl = blockIdx.x;
    int tid = threadIdx.x;
    __shared__ int s[1024];
    int v = (tid < N_) ? cnt[bl * N_ + tid] : 0;
    s[tid] = v;
    __syncthreads();
    for (int off = 1; off < 1024; off <<= 1) {
        int t = (tid >= off) ? s[tid - off] : 0;
        __syncthreads();
        s[tid] += t;
        __syncthreads();
    }
    if (tid < N_) {
        int excl = s[tid] - v;
        row_start[bl * N_ + tid] = excl;
        cursor[bl * N_ + tid] = excl;
    }
}

__global__ void scatter_kernel(const int* __restrict__ edge_index, int b0,
                               int* __restrict__ cursor, int* __restrict__ elist, int cE)
{
    int i = blockIdx.x * 256 + threadIdx.x;
    if (i >= cE) return;
    int bl = i / E_, ei = i % E_;
    int dst = edge_index[(long)(b0 + bl) * 2 * E_ + E_ + ei];
    int pos = atomicAdd(&cursor[bl * N_ + dst], 1);
    elist[bl * E_ + pos] = ei;
}

// ---------------------------------------------------------------------------
// Fused attention: one block per node, SINGLE pass over incoming edges.
// Unnormalized online accumulation: agg = (Σ ex·v)/Σex + skip;
// xsum = (Σ ex·x)/Σex per head.  ex = exp2((q·k + qW·x)·scale·log2e).
// Wave w == head w; butterfly shfl gives all lanes the head dot-sum.
// ---------------------------------------------------------------------------
__device__ __forceinline__ float d2(unsigned a, unsigned b)
{
    return bflo(a) * bflo(b) + bfhi(a) * bfhi(b);
}

__global__ void attn_kernel(const bf16* __restrict__ qkvs, const bf16* __restrict__ qWb,
                            const bf16* __restrict__ embh,
                            const int* __restrict__ edge_tokens, const int* __restrict__ edge_index,
                            const int* __restrict__ row_start, const int* __restrict__ cnt,
                            const int* __restrict__ elist, int b0,
                            bf16* __restrict__ aggb, bf16* __restrict__ xsumb)
{
    int base = blockIdx.x;              // bl*N_ + node
    int bl = base / N_;
    int tid = threadIdx.x;
    int l = tid & 63;
    int j0 = tid * 4;                   // 0..1023 (head = tid>>6)
    int jx = l * 4;                     // 0..255

    uint2 qq = *(const uint2*)(qkvs + (long)base * 4096 + j0);
    uint2 ww = *(const uint2*)(qWb + (long)base * 1024 + j0);

    int start = row_start[base];
    int deg = cnt[base];
    const int* el = elist + (long)bl * E_;
    const int* srcp = edge_index + (long)(b0 + bl) * 2 * E_;
    const int* tokp = edge_tokens + (long)(b0 + bl) * E_;

    float denom = 0.f;
    float v0 = 0.f, v1 = 0.f, v2 = 0.f, v3 = 0.f;
    float x0 = 0.f, x1 = 0.f, x2 = 0.f, x3 = 0.f;

    for (int t = 0; t < deg; ++t) {
        int ei = el[start + t];
        int src = srcp[ei];
        int tok = tokp[ei];
        const bf16* srow = qkvs + (long)(bl * N_ + src) * 4096;
        uint2 kk = *(const uint2*)(srow + 1024 + j0);
        uint2 vv = *(const uint2*)(srow + 2048 + j0);
        uint2 xx = *(const uint2*)(embh + (long)tok * 256 + jx);

        float s = d2(qq.x, kk.x) + d2(qq.y, kk.y) + d2(ww.x, xx.x) + d2(ww.y, xx.y);
        s += __shfl_xor(s, 32);
        s += __shfl_xor(s, 16);
        s += __shfl_xor(s, 8);
        s += __shfl_xor(s, 4);
        s += __shfl_xor(s, 2);
        s += __shfl_xor(s, 1);
        float ex = __builtin_amdgcn_exp2f(s * (SCALE_ * LOG2E));

        denom += ex;
        v0 += ex * bflo(vv.x); v1 += ex * bfhi(vv.x);
        v2 += ex * bflo(vv.y); v3 += ex * bfhi(vv.y);
        x0 += ex * bflo(xx.x); x1 += ex * bfhi(xx.x);
        x2 += ex * bflo(xx.y); x3 += ex * bfhi(xx.y);
    }

    float invd = (deg > 0) ? 1.f / denom : 0.f;
    uint2 sk = *(const uint2*)(qkvs + (long)base * 4096 + 3072 + j0);
    unsigned o0 = pack2(bflo(sk.x) + v0 * invd, bfhi(sk.x) + v1 * invd);
    unsigned o1 = pack2(bflo(sk.y) + v2 * invd, bfhi(sk.y) + v3 * invd);
    *(uint2*)(aggb + (long)base * HD_ + j0) = make_uint2(o0, o1);
    *(uint2*)(xsumb + (long)base * HD_ + j0) =
        make_uint2(pack2(x0 * invd, x1 * invd), pack2(x2 * invd, x3 * invd));
}

// ---------------------------------------------------------------------------
// fused mixed embed (inv rows then aa rows) -> bf16
// ---------------------------------------------------------------------------
__global__ void mixed2_kernel(const bf16* __restrict__ embh,
                              const int* __restrict__ inv_token, const int* __restrict__ inv_node,
                              const int* __restrict__ aa_token, const int* __restrict__ aa_node,
                              const float* __restrict__ graph_repr,
                              bf16* __restrict__ mixed_inv, bf16* __restrict__ aa_emb)
{
    int r = blockIdx.x;
    int d = threadIdx.x;
    if (r < B_ * L_) {
        int b = r / L_;
        float v = (float)embh[(long)inv_token[r] * D_ + d] +
                  graph_repr[((long)b * N_ + inv_node[r]) * D_ + d];
        mixed_inv[(long)r * D_ + d] = __float2bfloat16(v);
    } else {
        int r2 = r - B_ * L_;
        int b = r2 / A_;
        float v = (float)embh[(long)aa_token[r2] * D_ + d] +
                  graph_repr[((long)b * N_ + aa_node[r2]) * D_ + d];
        aa_emb[(long)r2 * D_ + d] = __float2bfloat16(v);
    }
}

// ---------------------------------------------------------------------------
// GRU via MFMA, gates in-register (round-9 structure)
// ---------------------------------------------------------------------------
__global__ __launch_bounds__(1024)
void gru_kernel(const bf16* __restrict__ gxT, const short8* __restrict__ WhhP,
                const float* __restrict__ b_hh, float* __restrict__ inv_out)
{
    __shared__ short hB[2][16 * 264];

    const int tid = threadIdx.x;
    const int lane = tid & 63;
    const int wave = tid >> 6;
    const int quad = lane >> 4, c16 = lane & 15;
    const int n0 = wave * 16 + c16;

    for (int i = tid; i < 2 * 16 * 264; i += 1024) ((short*)hB)[i] = 0;

    short8 wfr[8], wfz[8], wfn[8];
    #pragma unroll
    for (int tk = 0; tk < 8; ++tk) {
        wfr[tk] = WhhP[((0 * 16 + wave) * 8 + tk) * 64 + lane];
        wfz[tk] = WhhP[((1 * 16 + wave) * 8 + tk) * 64 + lane];
        wfn[tk] = WhhP[((2 * 16 + wave) * 8 + tk) * 64 + lane];
    }
    float bhr = b_hh[0 * 256 + n0];
    float bhz = b_hh[1 * 256 + n0];
    float bhn = b_hh[2 * 256 + n0];

    float myh0 = 0.f, myh1 = 0.f, myh2 = 0.f, myh3 = 0.f;

    const short* gbr = (const short*)gxT + (long)(0 * 256 + n0) * 16 + quad * 4;
    const short* gbz = gbr + 256 * 16;
    const short* gbn = gbr + 512 * 16;

    uint2 pxr = *(const uint2*)gbr;
    uint2 pxz = *(const uint2*)gbz;
    uint2 pxn = *(const uint2*)gbn;

    __syncthreads();

    int p = 0;
    for (int t = 0; t < L_; ++t) {
        uint2 xr2 = pxr, xz2 = pxz, xn2 = pxn;
        long noff = (long)((t + 1 < L_) ? t + 1 : t) * 12288;
        pxr = *(const uint2*)(gbr + noff);
        pxz = *(const uint2*)(gbz + noff);
        pxn = *(const uint2*)(gbn + noff);

        f32x4 ar = (f32x4){bhr, bhr, bhr, bhr};
        f32x4 az = (f32x4){bhz, bhz, bhz, bhz};
        f32x4 an = (f32x4){bhn, bhn, bhn, bhn};
        const short* hp = &hB[p][0];
        #pragma unroll
        for (int tk = 0; tk < 8; ++tk) {
            short8 a = *(const short8*)&hp[c16 * 264 + tk * 32 + quad * 8];
            ar = __builtin_amdgcn_mfma_f32_16x16x32_bf16(a, wfr[tk], ar, 0, 0, 0);
            az = __builtin_amdgcn_mfma_f32_16x16x32_bf16(a, wfz[tk], az, 0, 0, 0);
            an = __builtin_amdgcn_mfma_f32_16x16x32_bf16(a, wfn[tk], an, 0, 0, 0);
        }

        float xr[4] = {bflo(xr2.x), bfhi(xr2.x), bflo(xr2.y), bfhi(xr2.y)};
        float xz[4] = {bflo(xz2.x), bfhi(xz2.x), bflo(xz2.y), bfhi(xz2.y)};
        float xn[4] = {bflo(xn2.x), bfhi(xn2.x), bflo(xn2.y), bfhi(xn2.y)};
        float hold[4] = {myh0, myh1, myh2, myh3};
        float hn[4];
        short* hw = &hB[p ^ 1][0];
        #pragma unroll
        for (int r = 0; r < 4; ++r) {
            float rr = fsigm(xr[r] + ar[r]);
            float zz = fsigm(xz[r] + az[r]);
            float cc = ftanh(xn[r] + rr * an[r]);
            hn[r] = (1.f - zz) * cc + zz * hold[r];
            hw[(quad * 4 + r) * 264 + n0] = (short)rne1(hn[r]);
        }
        myh0 = hn[0]; myh1 = hn[1]; myh2 = hn[2]; myh3 = hn[3];
        p ^= 1;
        __syncthreads();
    }

    inv_out[(long)(quad * 4 + 0) * 256 + n0] = myh0;
    inv_out[(long)(quad * 4 + 1) * 256 + n0] = myh1;
    inv_out[(long)(quad * 4 + 2) * 256 + n0] = myh2;
    inv_out[(long)(quad * 4 + 3) * 256 + n0] = myh3;
}

// ---------------------------------------------------------------------------
// scores
// ---------------------------------------------------------------------------
__global__ void score_kernel(const float* __restrict__ aa_p, const bf16* __restrict__ aa_emb,
                             const float* __restrict__ inv, const float* __restrict__ Wab,
                             const float* __restrict__ bab, const float* __restrict__ mask,
                             float* __restrict__ out)
{
    int r = blockIdx.x * 4 + (threadIdx.x >> 6);
    int l = threadIdx.x & 63;
    int b = r / A_;
    float s = 0.f;
    for (int d = l; d < D_; d += 64)
        s += aa_p[(long)r * D_ + d] * inv[(long)b * D_ + d] +
             (float)aa_emb[(long)r * D_ + d] * Wab[d];
    #pragma unroll
    for (int off = 32; off; off >>= 1) s += __shfl_down(s, off);
    if (l == 0) {
        float lm = logf(mask[r]);
        const float MN = -3.4028234663852886e38f;
        if (!(lm >= MN)) lm = MN;
        out[r] = s + bab[0] + lm;
    }
}

// ---------------------------------------------------------------------------
// host
// ---------------------------------------------------------------------------
static inline size_t align256(size_t x) { return (x + 255) & ~(size_t)255; }

template <typename CT>
static void launch_pgemm(const bf16* A, const int* arows, const unsigned* Bp,
                         const float* bias, CT* C, int M, int K, int Nc, int relu,
                         long astride, int aoff, int colbase, int hslice, int addC,
                         int outT, int ncols, hipStream_t s)
{
    dim3 grid(ncols / TN, (M + TM - 1) / TM);
    pgemm_kernel<CT><<<grid, 256, 0, s>>>(A, arows, Bp, bias, C, M, K, Nc, relu,
                                          astride, aoff, colbase, hslice, addC, outT);
}

extern "C" void kernel_launch(void* const* d_in, const int* in_sizes, int n_in,
                              void* d_out, int out_size, void* d_ws, size_t ws_size,
                              hipStream_t stream)
{
    const int* node_tokens = (const int*)d_in[0];
    const int* edge_tokens = (const int*)d_in[1];
    const int* edge_index  = (const int*)d_in[2];
    const int* inv_token   = (const int*)d_in[3];
    const int* inv_node    = (const int*)d_in[4];
    const int* aa_token    = (const int*)d_in[5];
    const int* aa_node     = (const int*)d_in[6];
    const float* action_mask = (const float*)d_in[7];
    const float* emb   = (const float*)d_in[8];
    const float* Wq    = (const float*)d_in[9];
    const float* bq    = (const float*)d_in[10];
    const float* Wk    = (const float*)d_in[11];
    const float* bk    = (const float*)d_in[12];
    const float* Wv    = (const float*)d_in[13];
    const float* bv    = (const float*)d_in[14];
    const float* We    = (const float*)d_in[15];
    const float* Wskip = (const float*)d_in[16];
    const float* bskip = (const float*)d_in[17];
    const float* W1    = (const float*)d_in[18];
    const float* b1    = (const float*)d_in[19];
    const float* Wp    = (const float*)d_in[20];
    const float* bp    = (const float*)d_in[21];
    const float* W_ih  = (const float*)d_in[22];
    const float* W_hh  = (const float*)d_in[23];
    const float* b_ih  = (const float*)d_in[24];
    const float* b_hh  = (const float*)d_in[25];
    const float* Wab   = (const float*)d_in[26];
    const float* bab   = (const float*)d_in[27];
    const float* Wap   = (const float*)d_in[28];
    const float* bap   = (const float*)d_in[29];
    (void)in_sizes; (void)n_in; (void)out_size;

    char* base = (char*)d_ws;
    size_t off = 0;
    auto alloc = [&](size_t bytes) -> char* {
        char* p = base + off;
        off = align256(off + bytes);
        return p;
    };

    // persistent buffers
    const long VD = 50000L * 256;
    bf16*  embh       = (bf16*)alloc(VD * 2);
    float* graph_repr = (float*)alloc((size_t)B_ * N_ * D_ * 4);
    bf16*  mixed_inv  = (bf16*)alloc((size_t)B_ * L_ * D_ * 2);
    bf16*  inv_h      = (bf16*)alloc((size_t)B_ * L_ * D_ * 2);
    bf16*  gxT        = (bf16*)alloc((size_t)B_ * L_ * 768 * 2);
    float* inv_out    = (float*)alloc((size_t)B_ * 256 * 4);
    bf16*  aa_emb     = (bf16*)alloc((size_t)B_ * A_ * D_ * 2);
    float* aa_p       = (float*)alloc((size_t)B_ * A_ * 256 * 4);
    unsigned* qkvsP   = (unsigned*)alloc((size_t)128 * 4096 * 4);
    unsigned* WeP     = (unsigned*)alloc((size_t)128 * 1024 * 4);
    unsigned* W1P     = (unsigned*)alloc((size_t)512 * 256 * 4);
    unsigned* WpP     = (unsigned*)alloc((size_t)128 * 256 * 4);
    unsigned* WihP    = (unsigned*)alloc((size_t)128 * 768 * 4);
    unsigned* WapP    = (unsigned*)alloc((size_t)128 * 256 * 4);
    unsigned* WeTP    = (unsigned*)alloc((size_t)128 * 1024 * 4);
    short8* WhhP      = (short8*)alloc((size_t)24576 * 16);
    float* bias4096   = (float*)alloc(4096 * 4);
    size_t persist = off;

    // batch-chunk size
    int c = 16;
    while (c > 1) {
        size_t cN = (size_t)c * N_, cEs = (size_t)c * E_;
        size_t chunk = align256(cN * 4096 * 2)       // qkvs
                     + align256(cN * HD_ * 2)        // qWb
                     + align256(cN * HD_ * 2)        // aggb
                     + align256(cN * HD_ * 2)        // xsumb
                     + 3 * align256(cN * 4)
                     + align256(cEs * 4);
        if (persist + chunk <= ws_size) break;
        c >>= 1;
    }
    int cN = c * N_, cE = c * E_;

    bf16*  qkvs  = (bf16*)alloc((size_t)cN * 4096 * 2);
    bf16*  qWb   = (bf16*)alloc((size_t)cN * HD_ * 2);
    bf16*  aggb  = (bf16*)alloc((size_t)cN * HD_ * 2);
    bf16*  xsumb = (bf16*)alloc((size_t)cN * HD_ * 2);
    int*   cnt   = (int*)alloc((size_t)cN * 4);
    int*   rstart= (int*)alloc((size_t)cN * 4);
    int*   cursor= (int*)alloc((size_t)cN * 4);
    int*   elist = (int*)alloc((size_t)cE * 4);

    // ---- pre-pass ----
    convemb_kernel<<<(int)((VD / 4 + 255) / 256), 256, 0, stream>>>(emb, embh, VD / 4);
    pack_all_kernel<<<(PACK_ALL_TOT + 255) / 256, 256, 0, stream>>>(
        Wq, Wk, Wv, Wskip, We, W1, Wp, W_ih, Wap, W_hh, bq, bk, bv, bskip,
        qkvsP, WeP, W1P, WpP, WihP, WapP, WeTP, WhhP, bias4096);

    for (int b0 = 0; b0 < B_; b0 += c) {
        // CSR
        zero_int_kernel<<<(cN + 255) / 256, 256, 0, stream>>>(cnt, cN);
        count_kernel<<<(cE + 255) / 256, 256, 0, stream>>>(edge_index, b0, cnt, cE);
        scan_kernel<<<c, 1024, 0, stream>>>(cnt, rstart, cursor);
        scatter_kernel<<<(cE + 255) / 256, 256, 0, stream>>>(edge_index, b0, cursor,
                                                             elist, cE);
        // fused q|k|v|skip projection (gathered from embh)
        launch_pgemm<bf16>(embh, node_tokens + (long)b0 * N_, qkvsP, bias4096, qkvs,
                           cN, D_, 4096, 0, 256, 0, 0, 0, 0, 0, 4096, stream);
        // qW[n, h*256+d] = We_h @ q_h  (per-head K-slice of qkvs)
        launch_pgemm<bf16>(qkvs, nullptr, WeTP, nullptr, qWb,
                           cN, 256, 1024, 0, 4096, 0, 0, 1, 0, 0, 1024, stream);
        // fused attention (single pass, online softmax-denominator)
        attn_kernel<<<cN, 256, 0, stream>>>(qkvs, qWb, embh, edge_tokens, edge_index,
                                            rstart, cnt, elist, b0, aggb, xsumb);
        // aggb += xsum_h @ We_h ; relu
        launch_pgemm<bf16>(xsumb, nullptr, WeP, nullptr, aggb,
                           cN, 256, 1024, 1, 1024, 0, 0, 1, 1, 0, 1024, stream);
        // graph_repr = relu(aggb @ W1 + b1)
        launch_pgemm<float>(aggb, nullptr, W1P, b1,
                            graph_repr + (long)b0 * N_ * D_,
                            cN, HD_, D_, 1, 1024, 0, 0, 0, 0, 0, 256, stream);
    }

    // invariant + action embeds (fused)
    mixed2_kernel<<<B_ * L_ + B_ * A_, 256, 0, stream>>>(embh, inv_token, inv_node,
                                                         aa_token, aa_node, graph_repr,
                                                         mixed_inv, aa_emb);
    launch_pgemm<bf16>(mixed_inv, nullptr, WpP, bp, inv_h,
                       B_ * L_, D_, 256, 1, 256, 0, 0, 0, 0, 0, 256, stream);
    // gx GEMM writes the transposed [t][768][16] layout directly
    launch_pgemm<bf16>(inv_h, nullptr, WihP, b_ih, gxT,
                       B_ * L_, 256, 768, 0, 256, 0, 0, 0, 0, 1, 768, stream);
    gru_kernel<<<1, 1024, 0, stream>>>(gxT, WhhP, b_hh, inv_out);

    // action path
    launch_pgemm<float>(aa_emb, nullptr, WapP, bap, aa_p,
                        B_ * A_, D_, 256, 0, 256, 0, 0, 0, 0, 0, 256, stream);
    score_kernel<<<(B_ * A_) / 4, 256, 0, stream>>>(aa_p, aa_emb, inv_out, Wab, bab,
                                                    action_mask, (float*)d_out);
}

// Round 12
// 798.306 us; speedup vs baseline: 1.1952x; 1.0638x over previous
//
#include <hip/hip_runtime.h>
#include <hip/hip_bf16.h>
#include <float.h>
#include <math.h>

typedef __hip_bfloat16 bf16;

#define B_ 16
#define N_ 1000
#define E_ 4000
#define L_ 64
#define A_ 128
#define D_ 256
#define H_ 4
#define HD_ 1024
#define SCALE_ 0.0625f

typedef __attribute__((ext_vector_type(8))) short short8;
typedef __attribute__((ext_vector_type(4))) float f32x4;

union U4S8 { uint4 u; short8 s; };

__device__ __forceinline__ unsigned short f2bf(float f) {
    bf16 h = __float2bfloat16(f);
    return *reinterpret_cast<unsigned short*>(&h);
}
__device__ __forceinline__ unsigned pack2(float a, float b) {
    return (unsigned)f2bf(a) | ((unsigned)f2bf(b) << 16);
}
__device__ __forceinline__ unsigned short rne1(float a) {
    unsigned ua = __float_as_uint(a);
    ua += 0x7fff + ((ua >> 16) & 1);
    return (unsigned short)(ua >> 16);
}
__device__ __forceinline__ float bflo(unsigned u) { return __uint_as_float(u << 16); }
__device__ __forceinline__ float bfhi(unsigned u) { return __uint_as_float(u & 0xffff0000u); }

#define LOG2E 1.4426950408889634f
__device__ __forceinline__ float fsigm(float x) {
    return __builtin_amdgcn_rcpf(1.f + __builtin_amdgcn_exp2f(-LOG2E * x));
}
__device__ __forceinline__ float ftanh(float x) {
    return 1.f - 2.f * __builtin_amdgcn_rcpf(1.f + __builtin_amdgcn_exp2f(2.f * LOG2E * x));
}

// async global->LDS, 16B per lane
typedef const __attribute__((address_space(1))) unsigned int* gas_t;
typedef __attribute__((address_space(3))) unsigned int* las_t;
__device__ __forceinline__ void gld16(const void* g, void* l) {
    __builtin_amdgcn_global_load_lds((gas_t)g, (las_t)l, 16, 0, 0);
}

// ---------------------------------------------------------------------------
// Pre-pass: emb->bf16
// ---------------------------------------------------------------------------
__global__ void convemb_kernel(const float* __restrict__ src, bf16* __restrict__ dst, long n4)
{
    long i = (long)blockIdx.x * 256 + threadIdx.x;
    if (i >= n4) return;
    float4 v = *(const float4*)(src + i * 4);
    *(uint2*)(dst + i * 4) = make_uint2(pack2(v.x, v.y), pack2(v.z, v.w));
}

// ---------------------------------------------------------------------------
// Fused weight-pack pre-pass
// ---------------------------------------------------------------------------
__global__ void pack_all_kernel(const float* __restrict__ Wq, const float* __restrict__ Wk,
                                const float* __restrict__ Wv, const float* __restrict__ Wskip,
                                const float* __restrict__ We, const float* __restrict__ W1,
                                const float* __restrict__ Wp, const float* __restrict__ W_ih,
                                const float* __restrict__ Wap, const float* __restrict__ W_hh,
                                const float* __restrict__ bq, const float* __restrict__ bk,
                                const float* __restrict__ bv, const float* __restrict__ bskip,
                                unsigned* __restrict__ qkvsP, unsigned* __restrict__ WeP,
                                unsigned* __restrict__ W1P, unsigned* __restrict__ WpP,
                                unsigned* __restrict__ WihP, unsigned* __restrict__ WapP,
                                unsigned* __restrict__ WeTP,
                                short8* __restrict__ WhhP, float* __restrict__ bias4096)
{
    int i = blockIdx.x * 256 + threadIdx.x;
    if (i < 524288) {                       // qkvsP: 128 k2 x 4096
        int k2 = i >> 12, n = i & 4095;
        const float* s = (n < 1024) ? Wq : (n < 2048) ? Wk : (n < 3072) ? Wv : Wskip;
        int col = n & 1023;
        qkvsP[i] = pack2(s[(long)(2 * k2) * 1024 + col], s[(long)(2 * k2 + 1) * 1024 + col]);
        return;
    }
    i -= 524288;
    if (i < 131072) {                       // WeP: 128 x 1024
        int k2 = i >> 10, n = i & 1023;
        WeP[i] = pack2(We[(long)(2 * k2) * 1024 + n], We[(long)(2 * k2 + 1) * 1024 + n]);
        return;
    }
    i -= 131072;
    if (i < 131072) {                       // W1P: 512 k2 x 256
        int k2 = i >> 8, n = i & 255;
        W1P[i] = pack2(W1[(long)(2 * k2) * 256 + n], W1[(long)(2 * k2 + 1) * 256 + n]);
        return;
    }
    i -= 131072;
    if (i < 32768) {                        // WpP: 128 x 256
        int k2 = i >> 8, n = i & 255;
        WpP[i] = pack2(Wp[(long)(2 * k2) * 256 + n], Wp[(long)(2 * k2 + 1) * 256 + n]);
        return;
    }
    i -= 32768;
    if (i < 98304) {                        // WihP (transposed src [768,256]): 128 k2 x 768
        int k2 = i / 768, n = i % 768;
        WihP[i] = pack2(W_ih[(long)n * 256 + 2 * k2], W_ih[(long)n * 256 + 2 * k2 + 1]);
        return;
    }
    i -= 98304;
    if (i < 32768) {                        // WapP: 128 x 256 (unused now, kept for layout)
        int k2 = i >> 8, n = i & 255;
        WapP[i] = pack2(Wap[(long)(2 * k2) * 256 + n], Wap[(long)(2 * k2 + 1) * 256 + n]);
        return;
    }
    i -= 32768;
    if (i < 131072) {                       // WeTP: 128 k2 x 1024 (per-head transpose)
        int k2 = i >> 10, n = i & 1023;
        int d = n & 255, hb = n & ~255;
        WeTP[i] = pack2(We[(long)d * 1024 + hb + 2 * k2],
                        We[(long)d * 1024 + hb + 2 * k2 + 1]);
        return;
    }
    i -= 131072;
    if (i < 24576) {                        // WhhP MFMA B-frag stream (48 tiles)
        int lane = i & 63, tk = (i >> 6) & 7, tile = i >> 9;
        int n = tile * 16 + (lane & 15);
        const float* wp = W_hh + (long)n * 256 + tk * 32 + (lane >> 4) * 8;
        float4 w0 = *(const float4*)wp;
        float4 w1 = *(const float4*)(wp + 4);
        U4S8 u;
        u.u = make_uint4(pack2(w0.x, w0.y), pack2(w0.z, w0.w),
                         pack2(w1.x, w1.y), pack2(w1.z, w1.w));
        WhhP[i] = u.s;
        return;
    }
    i -= 24576;
    if (i < 4096) {                         // bias4096
        int q = i >> 10, c = i & 1023;
        bias4096[i] = ((q == 0) ? bq : (q == 1) ? bk : (q == 2) ? bv : bskip)[c];
    }
}
#define PACK_ALL_TOT (524288 + 131072 + 131072 + 32768 + 98304 + 32768 + 131072 + 24576 + 4096)

// ---------------------------------------------------------------------------
// MFMA GEMM v2 (round-11 engine, unchanged)
// ---------------------------------------------------------------------------
#define TM 128
#define TN 128
#define TK 32
#define BSTR 132

template <typename CT>
__global__ __launch_bounds__(256)
void pgemm_kernel(const bf16* __restrict__ A, const int* __restrict__ arows,
                  const unsigned* __restrict__ Bp, const float* __restrict__ bias,
                  CT* __restrict__ C, int M, int K, int Nc, int relu_out,
                  long astride, int aoff, int colbase, int hslice, int addC, int outT)
{
    __shared__ short    As[TM * TK];
    __shared__ unsigned Bs[(TK / 2) * BSTR];

    const int tid  = threadIdx.x;
    const int lane = tid & 63;
    const int wave = tid >> 6;
    const int wm = wave >> 1, wn = wave & 1;
    const int quad = lane >> 4, c16 = lane & 15;
    const long row0 = (long)blockIdx.y * TM;
    const int  col0 = colbase + blockIdx.x * TN;
    const int  aoff2 = aoff + (hslice ? (col0 & ~255) : 0);

    const int r0 = wave * 32 + (lane >> 2);
    const int cseg = (lane & 3) * 8;
    long gr0 = row0 + r0;      if (gr0 > M - 1) gr0 = M - 1;
    long gr1 = row0 + r0 + 16; if (gr1 > M - 1) gr1 = M - 1;
    long ar0 = arows ? (long)arows[gr0] : gr0;
    long ar1 = arows ? (long)arows[gr1] : gr1;
    const short* Ag0 = (const short*)A + ar0 * astride + aoff2 + cseg;
    const short* Ag1 = (const short*)A + ar1 * astride + aoff2 + cseg;
    short* Ld0 = &As[wave * 1024];
    short* Ld1 = &As[wave * 1024 + 512];

    const int sn2 = tid & 63;
    const int skk = wave * 4;

    f32x4 acc[4][4];
    #pragma unroll
    for (int i = 0; i < 4; ++i)
        #pragma unroll
        for (int j = 0; j < 4; ++j)
            acc[i][j] = (f32x4){0.f, 0.f, 0.f, 0.f};

    for (int k0 = 0; k0 < K; k0 += TK) {
        gld16(Ag0 + k0, Ld0);
        gld16(Ag1 + k0, Ld1);
        #pragma unroll
        for (int i = 0; i < 4; ++i) {
            int kk2 = skk + i;
            *(uint2*)&Bs[kk2 * BSTR + sn2 * 2] =
                *(const uint2*)&Bp[(long)(k0 / 2 + kk2) * Nc + col0 + sn2 * 2];
        }
        __syncthreads();

        short8 af[4];
        U4S8   bfr[4];
        #pragma unroll
        for (int mi = 0; mi < 4; ++mi) {
            int m = wm * 64 + mi * 16 + c16;
            af[mi] = *(const short8*)&As[m * 32 + quad * 8];
        }
        #pragma unroll
        for (int ni = 0; ni < 4; ++ni) {
            int n = wn * 64 + ni * 16 + c16;
            uint4 u;
            u.x = Bs[(quad * 4 + 0) * BSTR + n];
            u.y = Bs[(quad * 4 + 1) * BSTR + n];
            u.z = Bs[(quad * 4 + 2) * BSTR + n];
            u.w = Bs[(quad * 4 + 3) * BSTR + n];
            bfr[ni].u = u;
        }
        #pragma unroll
        for (int mi = 0; mi < 4; ++mi)
            #pragma unroll
            for (int ni = 0; ni < 4; ++ni)
                acc[mi][ni] = __builtin_amdgcn_mfma_f32_16x16x32_bf16(
                    af[mi], bfr[ni].s, acc[mi][ni], 0, 0, 0);
        __syncthreads();
    }

    #pragma unroll
    for (int ni = 0; ni < 4; ++ni) {
        int col = col0 + wn * 64 + ni * 16 + c16;
        float bv = bias ? bias[col] : 0.f;
        #pragma unroll
        for (int mi = 0; mi < 4; ++mi) {
            long row = row0 + wm * 64 + mi * 16 + quad * 4;
            #pragma unroll
            for (int r = 0; r < 4; ++r) {
                if (row + r >= M) continue;
                float v = acc[mi][ni][r] + bv;
                if (addC) v += (float)C[(row + r) * Nc + col];
                if (relu_out) v = fmaxf(v, 0.f);
                if (outT) {
                    long rr = row + r;
                    int t = (int)(rr & 63), b = (int)(rr >> 6);
                    C[((long)t * Nc + col) * 16 + b] = (CT)v;
                } else {
                    C[(row + r) * Nc + col] = (CT)v;
                }
            }
        }
    }
}

// ---------------------------------------------------------------------------
// CSR build
// ---------------------------------------------------------------------------
__global__ void zero_int_kernel(int* __restrict__ p, int n)
{
    int i = blockIdx.x * 256 + threadIdx.x;
    if (i < n) p[i] = 0;
}

__global__ void count_kernel(const int* __restrict__ edge_index, int b0,
                             int* __restrict__ cnt, int cE)
{
    int i = blockIdx.x * 256 + threadIdx.x;
    if (i >= cE) return;
    int bl = i / E_, ei = i % E_;
    int dst = edge_index[(long)(b0 + bl) * 2 * E_ + E_ + ei];
    atomicAdd(&cnt[bl * N_ + dst], 1);
}

__global__ __launch_bounds__(1024)
void scan_kernel(const int* __restrict__ cnt, int* __restrict__ row_start,
                 int* __restrict__ cursor)
{
    int bl = blockIdx.x;
    int tid = threadIdx.x;
    __shared__ int s[1024];
    int v = (tid < N_) ? cnt[bl * N_ + tid] : 0;
    s[tid] = v;
    __syncthreads();
    for (int off = 1; off < 1024; off <<= 1) {
        int t = (tid >= off) ? s[tid - off] : 0;
        __syncthreads();
        s[tid] += t;
        __syncthreads();
    }
    if (tid < N_) {
        int excl = s[tid] - v;
        row_start[bl * N_ + tid] = excl;
        cursor[bl * N_ + tid] = excl;
    }
}

__global__ void scatter_kernel(const int* __restrict__ edge_index, int b0,
                               int* __restrict__ cursor, int* __restrict__ elist, int cE)
{
    int i = blockIdx.x * 256 + threadIdx.x;
    if (i >= cE) return;
    int bl = i / E_, ei = i % E_;
    int dst = edge_index[(long)(b0 + bl) * 2 * E_ + E_ + ei];
    int pos = atomicAdd(&cursor[bl * N_ + dst], 1);
    elist[bl * E_ + pos] = ei;
}

// ---------------------------------------------------------------------------
// Fused attention, software-pipelined edge loop (prefetch next k/v/x)
// ---------------------------------------------------------------------------
__device__ __forceinline__ float d2(unsigned a, unsigned b)
{
    return bflo(a) * bflo(b) + bfhi(a) * bfhi(b);
}

__global__ void attn_kernel(const bf16* __restrict__ qkvs, const bf16* __restrict__ qWb,
                            const bf16* __restrict__ embh,
                            const int* __restrict__ edge_tokens, const int* __restrict__ edge_index,
                            const int* __restrict__ row_start, const int* __restrict__ cnt,
                            const int* __restrict__ elist, int b0,
                            bf16* __restrict__ aggb, bf16* __restrict__ xsumb)
{
    int base = blockIdx.x;
    int bl = base / N_;
    int tid = threadIdx.x;
    int l = tid & 63;
    int j0 = tid * 4;
    int jx = l * 4;

    uint2 qq = *(const uint2*)(qkvs + (long)base * 4096 + j0);
    uint2 ww = *(const uint2*)(qWb + (long)base * 1024 + j0);

    int start = row_start[base];
    int deg = cnt[base];
    const int* el = elist + (long)bl * E_;
    const int* srcp = edge_index + (long)(b0 + bl) * 2 * E_;
    const int* tokp = edge_tokens + (long)(b0 + bl) * E_;

    float denom = 0.f;
    float v0 = 0.f, v1 = 0.f, v2 = 0.f, v3 = 0.f;
    float x0 = 0.f, x1 = 0.f, x2 = 0.f, x3 = 0.f;

    uint2 kk = make_uint2(0, 0), vv = make_uint2(0, 0), xx = make_uint2(0, 0);
    if (deg > 0) {
        int e0 = el[start];
        int s0 = srcp[e0], t0 = tokp[e0];
        const bf16* srow = qkvs + (long)(bl * N_ + s0) * 4096;
        kk = *(const uint2*)(srow + 1024 + j0);
        vv = *(const uint2*)(srow + 2048 + j0);
        xx = *(const uint2*)(embh + (long)t0 * 256 + jx);
    }

    for (int t = 0; t < deg; ++t) {
        uint2 ck = kk, cv = vv, cx = xx;
        if (t + 1 < deg) {
            int ne = el[start + t + 1];
            int ns = srcp[ne], nt = tokp[ne];
            const bf16* srow = qkvs + (long)(bl * N_ + ns) * 4096;
            kk = *(const uint2*)(srow + 1024 + j0);
            vv = *(const uint2*)(srow + 2048 + j0);
            xx = *(const uint2*)(embh + (long)nt * 256 + jx);
        }

        float s = d2(qq.x, ck.x) + d2(qq.y, ck.y) + d2(ww.x, cx.x) + d2(ww.y, cx.y);
        s += __shfl_xor(s, 32);
        s += __shfl_xor(s, 16);
        s += __shfl_xor(s, 8);
        s += __shfl_xor(s, 4);
        s += __shfl_xor(s, 2);
        s += __shfl_xor(s, 1);
        float ex = __builtin_amdgcn_exp2f(s * (SCALE_ * LOG2E));

        denom += ex;
        v0 += ex * bflo(cv.x); v1 += ex * bfhi(cv.x);
        v2 += ex * bflo(cv.y); v3 += ex * bfhi(cv.y);
        x0 += ex * bflo(cx.x); x1 += ex * bfhi(cx.x);
        x2 += ex * bflo(cx.y); x3 += ex * bfhi(cx.y);
    }

    float invd = (deg > 0) ? 1.f / denom : 0.f;
    uint2 sk = *(const uint2*)(qkvs + (long)base * 4096 + 3072 + j0);
    unsigned o0 = pack2(bflo(sk.x) + v0 * invd, bfhi(sk.x) + v1 * invd);
    unsigned o1 = pack2(bflo(sk.y) + v2 * invd, bfhi(sk.y) + v3 * invd);
    *(uint2*)(aggb + (long)base * HD_ + j0) = make_uint2(o0, o1);
    *(uint2*)(xsumb + (long)base * HD_ + j0) =
        make_uint2(pack2(x0 * invd, x1 * invd), pack2(x2 * invd, x3 * invd));
}

// ---------------------------------------------------------------------------
// fused mixed embed (inv rows then aa rows) -> bf16; graph_repr is bf16 now
// ---------------------------------------------------------------------------
__global__ void mixed2_kernel(const bf16* __restrict__ embh,
                              const int* __restrict__ inv_token, const int* __restrict__ inv_node,
                              const int* __restrict__ aa_token, const int* __restrict__ aa_node,
                              const bf16* __restrict__ graph_repr,
                              bf16* __restrict__ mixed_inv, bf16* __restrict__ aa_emb)
{
    int r = blockIdx.x;
    int d = threadIdx.x;
    if (r < B_ * L_) {
        int b = r / L_;
        float v = (float)embh[(long)inv_token[r] * D_ + d] +
                  (float)graph_repr[((long)b * N_ + inv_node[r]) * D_ + d];
        mixed_inv[(long)r * D_ + d] = __float2bfloat16(v);
    } else {
        int r2 = r - B_ * L_;
        int b = r2 / A_;
        float v = (float)embh[(long)aa_token[r2] * D_ + d] +
                  (float)graph_repr[((long)b * N_ + aa_node[r2]) * D_ + d];
        aa_emb[(long)r2 * D_ + d] = __float2bfloat16(v);
    }
}

// ---------------------------------------------------------------------------
// GRU via MFMA, 4 blocks x 4 batches.  Block g owns batches g*4..g*4+3 at
// MFMA A-rows {0,4,8,12} so lane (quad, r=0) holds valid gates for batch
// g*4+quad -> elementwise is ONE element per lane (VALU /4 vs round 9).
// Unused A-rows stay zero; MFMA count unchanged.  gx prefetched 1 step ahead.
// ---------------------------------------------------------------------------
__global__ __launch_bounds__(1024)
void gru_kernel(const bf16* __restrict__ gxT, const short8* __restrict__ WhhP,
                const float* __restrict__ b_hh, float* __restrict__ inv_out)
{
    __shared__ short hB[2][16 * 264];

    const int tid = threadIdx.x;
    const int lane = tid & 63;
    const int wave = tid >> 6;
    const int quad = lane >> 4, c16 = lane & 15;
    const int n0 = wave * 16 + c16;          // gate/hidden column 0..255
    const int bb = blockIdx.x * 4 + quad;    // global batch for this lane

    for (int i = tid; i < 2 * 16 * 264; i += 1024) ((short*)hB)[i] = 0;

    short8 wfr[8], wfz[8], wfn[8];
    #pragma unroll
    for (int tk = 0; tk < 8; ++tk) {
        wfr[tk] = WhhP[((0 * 16 + wave) * 8 + tk) * 64 + lane];
        wfz[tk] = WhhP[((1 * 16 + wave) * 8 + tk) * 64 + lane];
        wfn[tk] = WhhP[((2 * 16 + wave) * 8 + tk) * 64 + lane];
    }
    float bhr = b_hh[0 * 256 + n0];
    float bhz = b_hh[1 * 256 + n0];
    float bhn = b_hh[2 * 256 + n0];

    float myh = 0.f;

    const unsigned short* g_r = (const unsigned short*)gxT + (long)n0 * 16 + bb;
    const unsigned short* g_z = g_r + 256 * 16;
    const unsigned short* g_n = g_r + 512 * 16;

    unsigned short pr = g_r[0], pz = g_z[0], pn = g_n[0];

    __syncthreads();

    int p = 0;
    for (int t = 0; t < L_; ++t) {
        float xr = __uint_as_float((unsigned)pr << 16);
        float xz = __uint_as_float((unsigned)pz << 16);
        float xn = __uint_as_float((unsigned)pn << 16);
        long noff = (long)((t + 1 < L_) ? t + 1 : t) * 12288;
        pr = g_r[noff]; pz = g_z[noff]; pn = g_n[noff];

        f32x4 ar = (f32x4){bhr, bhr, bhr, bhr};
        f32x4 az = (f32x4){bhz, bhz, bhz, bhz};
        f32x4 an = (f32x4){bhn, bhn, bhn, bhn};
        const short* hp = &hB[p][0];
        #pragma unroll
        for (int tk = 0; tk < 8; ++tk) {
            short8 a = *(const short8*)&hp[c16 * 264 + tk * 32 + quad * 8];
            ar = __builtin_amdgcn_mfma_f32_16x16x32_bf16(a, wfr[tk], ar, 0, 0, 0);
            az = __builtin_amdgcn_mfma_f32_16x16x32_bf16(a, wfz[tk], az, 0, 0, 0);
            an = __builtin_amdgcn_mfma_f32_16x16x32_bf16(a, wfn[tk], an, 0, 0, 0);
        }

        // valid gates at acc element 0 (A-row quad*4 == batch slot)
        float rr = fsigm(xr + ar[0]);
        float zz = fsigm(xz + az[0]);
        float cc = ftanh(xn + rr * an[0]);
        myh = (1.f - zz) * cc + zz * myh;
        hB[p ^ 1][(quad * 4) * 264 + n0] = (short)rne1(myh);
        p ^= 1;
        __syncthreads();
    }

    inv_out[(long)bb * 256 + n0] = myh;
}

// ---------------------------------------------------------------------------
// uprep: u[b,d] = Wab[d] + Σ_o Wap[d,o]·inv[b,o];  s0[b] = bab + bap·inv[b]
// (folds the aa_p GEMM into score algebraically)
// ---------------------------------------------------------------------------
__global__ void uprep_kernel(const float* __restrict__ Wap, const float* __restrict__ Wab,
                             const float* __restrict__ bap, const float* __restrict__ bab,
                             const float* __restrict__ inv, float* __restrict__ u,
                             float* __restrict__ s0)
{
    int b = blockIdx.x, d = threadIdx.x;
    __shared__ float iv[256];
    iv[d] = inv[(long)b * 256 + d];
    __syncthreads();
    float s = Wab[d];
    const float* wr = Wap + (long)d * 256;
    #pragma unroll 8
    for (int o = 0; o < 256; ++o) s += wr[o] * iv[o];
    u[(long)b * 256 + d] = s;
    if (d == 0) {
        float t = bab[0];
        for (int o = 0; o < 256; ++o) t += bap[o] * iv[o];
        s0[b] = t;
    }
}

// ---------------------------------------------------------------------------
// scores: out[r] = aa_emb[r]·u[b] + s0[b] + log-mask
// ---------------------------------------------------------------------------
__global__ void score_kernel(const bf16* __restrict__ aa_emb, const float* __restrict__ u,
                             const float* __restrict__ s0, const float* __restrict__ mask,
                             float* __restrict__ out)
{
    int r = blockIdx.x * 4 + (threadIdx.x >> 6);
    int l = threadIdx.x & 63;
    int b = r / A_;
    float s = 0.f;
    for (int d = l; d < D_; d += 64)
        s += (float)aa_emb[(long)r * D_ + d] * u[(long)b * D_ + d];
    #pragma unroll
    for (int off = 32; off; off >>= 1) s += __shfl_down(s, off);
    if (l == 0) {
        float lm = logf(mask[r]);
        const float MN = -3.4028234663852886e38f;
        if (!(lm >= MN)) lm = MN;
        out[r] = s + s0[b] + lm;
    }
}

// ---------------------------------------------------------------------------
// host
// ---------------------------------------------------------------------------
static inline size_t align256(size_t x) { return (x + 255) & ~(size_t)255; }

template <typename CT>
static void launch_pgemm(const bf16* A, const int* arows, const unsigned* Bp,
                         const float* bias, CT* C, int M, int K, int Nc, int relu,
                         long astride, int aoff, int colbase, int hslice, int addC,
                         int outT, int ncols, hipStream_t s)
{
    dim3 grid(ncols / TN, (M + TM - 1) / TM);
    pgemm_kernel<CT><<<grid, 256, 0, s>>>(A, arows, Bp, bias, C, M, K, Nc, relu,
                                          astride, aoff, colbase, hslice, addC, outT);
}

extern "C" void kernel_launch(void* const* d_in, const int* in_sizes, int n_in,
                              void* d_out, int out_size, void* d_ws, size_t ws_size,
                              hipStream_t stream)
{
    const int* node_tokens = (const int*)d_in[0];
    const int* edge_tokens = (const int*)d_in[1];
    const int* edge_index  = (const int*)d_in[2];
    const int* inv_token   = (const int*)d_in[3];
    const int* inv_node    = (const int*)d_in[4];
    const int* aa_token    = (const int*)d_in[5];
    const int* aa_node     = (const int*)d_in[6];
    const float* action_mask = (const float*)d_in[7];
    const float* emb   = (const float*)d_in[8];
    const float* Wq    = (const float*)d_in[9];
    const float* bq    = (const float*)d_in[10];
    const float* Wk    = (const float*)d_in[11];
    const float* bk    = (const float*)d_in[12];
    const float* Wv    = (const float*)d_in[13];
    const float* bv    = (const float*)d_in[14];
    const float* We    = (const float*)d_in[15];
    const float* Wskip = (const float*)d_in[16];
    const float* bskip = (const float*)d_in[17];
    const float* W1    = (const float*)d_in[18];
    const float* b1    = (const float*)d_in[19];
    const float* Wp    = (const float*)d_in[20];
    const float* bp    = (const float*)d_in[21];
    const float* W_ih  = (const float*)d_in[22];
    const float* W_hh  = (const float*)d_in[23];
    const float* b_ih  = (const float*)d_in[24];
    const float* b_hh  = (const float*)d_in[25];
    const float* Wab   = (const float*)d_in[26];
    const float* bab   = (const float*)d_in[27];
    const float* Wap   = (const float*)d_in[28];
    const float* bap   = (const float*)d_in[29];
    (void)in_sizes; (void)n_in; (void)out_size;

    char* base = (char*)d_ws;
    size_t off = 0;
    auto alloc = [&](size_t bytes) -> char* {
        char* p = base + off;
        off = align256(off + bytes);
        return p;
    };

    // persistent buffers
    const long VD = 50000L * 256;
    bf16*  embh       = (bf16*)alloc(VD * 2);
    bf16*  graph_repr = (bf16*)alloc((size_t)B_ * N_ * D_ * 2);
    bf16*  mixed_inv  = (bf16*)alloc((size_t)B_ * L_ * D_ * 2);
    bf16*  inv_h      = (bf16*)alloc((size_t)B_ * L_ * D_ * 2);
    bf16*  gxT        = (bf16*)alloc((size_t)B_ * L_ * 768 * 2);
    float* inv_out    = (float*)alloc((size_t)B_ * 256 * 4);
    bf16*  aa_emb     = (bf16*)alloc((size_t)B_ * A_ * D_ * 2);
    float* ubuf       = (float*)alloc((size_t)B_ * 256 * 4);
    float* s0buf      = (float*)alloc((size_t)B_ * 4);
    unsigned* qkvsP   = (unsigned*)alloc((size_t)128 * 4096 * 4);
    unsigned* WeP     = (unsigned*)alloc((size_t)128 * 1024 * 4);
    unsigned* W1P     = (unsigned*)alloc((size_t)512 * 256 * 4);
    unsigned* WpP     = (unsigned*)alloc((size_t)128 * 256 * 4);
    unsigned* WihP    = (unsigned*)alloc((size_t)128 * 768 * 4);
    unsigned* WapP    = (unsigned*)alloc((size_t)128 * 256 * 4);
    unsigned* WeTP    = (unsigned*)alloc((size_t)128 * 1024 * 4);
    short8* WhhP      = (short8*)alloc((size_t)24576 * 16);
    float* bias4096   = (float*)alloc(4096 * 4);
    size_t persist = off;

    // batch-chunk size
    int c = 16;
    while (c > 1) {
        size_t cN = (size_t)c * N_, cEs = (size_t)c * E_;
        size_t chunk = align256(cN * 4096 * 2)
                     + align256(cN * HD_ * 2)
                     + align256(cN * HD_ * 2)
                     + align256(cN * HD_ * 2)
                     + 3 * align256(cN * 4)
                     + align256(cEs * 4);
        if (persist + chunk <= ws_size) break;
        c >>= 1;
    }
    int cN = c * N_, cE = c * E_;

    bf16*  qkvs  = (bf16*)alloc((size_t)cN * 4096 * 2);
    bf16*  qWb   = (bf16*)alloc((size_t)cN * HD_ * 2);
    bf16*  aggb  = (bf16*)alloc((size_t)cN * HD_ * 2);
    bf16*  xsumb = (bf16*)alloc((size_t)cN * HD_ * 2);
    int*   cnt   = (int*)alloc((size_t)cN * 4);
    int*   rstart= (int*)alloc((size_t)cN * 4);
    int*   cursor= (int*)alloc((size_t)cN * 4);
    int*   elist = (int*)alloc((size_t)cE * 4);

    // ---- pre-pass ----
    convemb_kernel<<<(int)((VD / 4 + 255) / 256), 256, 0, stream>>>(emb, embh, VD / 4);
    pack_all_kernel<<<(PACK_ALL_TOT + 255) / 256, 256, 0, stream>>>(
        Wq, Wk, Wv, Wskip, We, W1, Wp, W_ih, Wap, W_hh, bq, bk, bv, bskip,
        qkvsP, WeP, W1P, WpP, WihP, WapP, WeTP, WhhP, bias4096);

    for (int b0 = 0; b0 < B_; b0 += c) {
        // CSR
        zero_int_kernel<<<(cN + 255) / 256, 256, 0, stream>>>(cnt, cN);
        count_kernel<<<(cE + 255) / 256, 256, 0, stream>>>(edge_index, b0, cnt, cE);
        scan_kernel<<<c, 1024, 0, stream>>>(cnt, rstart, cursor);
        scatter_kernel<<<(cE + 255) / 256, 256, 0, stream>>>(edge_index, b0, cursor,
                                                             elist, cE);
        // fused q|k|v|skip projection (gathered from embh)
        launch_pgemm<bf16>(embh, node_tokens + (long)b0 * N_, qkvsP, bias4096, qkvs,
                           cN, D_, 4096, 0, 256, 0, 0, 0, 0, 0, 4096, stream);
        // qW[n, h*256+d] = We_h @ q_h  (per-head K-slice of qkvs)
        launch_pgemm<bf16>(qkvs, nullptr, WeTP, nullptr, qWb,
                           cN, 256, 1024, 0, 4096, 0, 0, 1, 0, 0, 1024, stream);
        // fused attention (single pass, pipelined edge loop)
        attn_kernel<<<cN, 256, 0, stream>>>(qkvs, qWb, embh, edge_tokens, edge_index,
                                            rstart, cnt, elist, b0, aggb, xsumb);
        // aggb += xsum_h @ We_h ; relu
        launch_pgemm<bf16>(xsumb, nullptr, WeP, nullptr, aggb,
                           cN, 256, 1024, 1, 1024, 0, 0, 1, 1, 0, 1024, stream);
        // graph_repr = relu(aggb @ W1 + b1)  (bf16 out)
        launch_pgemm<bf16>(aggb, nullptr, W1P, b1,
                           graph_repr + (long)b0 * N_ * D_,
                           cN, HD_, D_, 1, 1024, 0, 0, 0, 0, 0, 256, stream);
    }

    // invariant + action embeds (fused)
    mixed2_kernel<<<B_ * L_ + B_ * A_, 256, 0, stream>>>(embh, inv_token, inv_node,
                                                         aa_token, aa_node, graph_repr,
                                                         mixed_inv, aa_emb);
    launch_pgemm<bf16>(mixed_inv, nullptr, WpP, bp, inv_h,
                       B_ * L_, D_, 256, 1, 256, 0, 0, 0, 0, 0, 256, stream);
    // gx GEMM writes the transposed [t][768][16] layout directly
    launch_pgemm<bf16>(inv_h, nullptr, WihP, b_ih, gxT,
                       B_ * L_, 256, 768, 0, 256, 0, 0, 0, 0, 1, 768, stream);
    gru_kernel<<<4, 1024, 0, stream>>>(gxT, WhhP, b_hh, inv_out);

    // action path (aa_p GEMM folded away)
    uprep_kernel<<<B_, 256, 0, stream>>>(Wap, Wab, bap, bab, inv_out, ubuf, s0buf);
    score_kernel<<<(B_ * A_) / 4, 256, 0, stream>>>(aa_emb, ubuf, s0buf,
                                                    action_mask, (float*)d_out);
}